// Round 3
// baseline (229.928 us; speedup 1.0000x reference)
//
#include <hip/hip_runtime.h>
#include <hip/hip_bf16.h>
#include <hip/hip_fp16.h>

#define N_NODES 50000
#define N_EDGES 800000
#define DIM 128
#define NGROUPS (N_NODES / 16)                 // 3125 (exact)
#define LROW2 132                              // LDS row stride (floats)
#define KBUCKET 196                            // buckets of 256 nodes (dst>>8)
#define BCAP 5120                              // bucket capacity (mean 4096, ~16 sigma)
#define EPB 2000                               // edges per phase-A block (400 blocks)
#define NSLOT (KBUCKET*256)                    // 50176 perm slots (176 invalid tail)

typedef __attribute__((ext_vector_type(8))) _Float16 hfrag8;
typedef __attribute__((ext_vector_type(4))) float f32x4;
typedef _Float16 h2 __attribute__((ext_vector_type(2)));

__device__ __forceinline__ h2 u2h(uint u){ union{uint u; h2 h;} c; c.u = u; return c.h; }

// sum across the 16 lanes of a DPP row; all 16 lanes receive the total.
// row_ror:{8,4,2,1} circulant reduction -- pure VALU, no DS pipe.
__device__ __forceinline__ float rowsum16(float p) {
  union { float f; int i; } a, b;
  a.f = p;
  b.i = __builtin_amdgcn_update_dpp(0, a.i, 0x128, 0xF, 0xF, true); a.f += b.f;
  b.i = __builtin_amdgcn_update_dpp(0, a.i, 0x124, 0xF, 0xF, true); a.f += b.f;
  b.i = __builtin_amdgcn_update_dpp(0, a.i, 0x122, 0xF, 0xF, true); a.f += b.f;
  b.i = __builtin_amdgcn_update_dpp(0, a.i, 0x121, 0xF, 0xF, true); a.f += b.f;
  return a.f;
}

// ---------------- CSR build phase A: bucket scatter ----------------
// bucketdata entry packed: (src << 8) | (dst & 255)

__global__ __launch_bounds__(256) void bucket_scatter_k(
    const int* __restrict__ src, const int* __restrict__ dst,
    int* __restrict__ bucket_cnt, uint* __restrict__ bucketdata)
{
  __shared__ int cnt[KBUCKET], base[KBUCKET], cur[KBUCKET];
  int tid = threadIdx.x;
  for (int t = tid; t < KBUCKET; t += 256) { cnt[t] = 0; cur[t] = 0; }
  __syncthreads();
  int e0 = blockIdx.x * EPB;
  int dreg[8];                                 // cache dst: read once, use twice
  #pragma unroll
  for (int it = 0; it < 8; it++) {
    int i = it*256 + tid;
    dreg[it] = (i < EPB) ? dst[e0 + i] : -1;
    if (i < EPB) atomicAdd(&cnt[dreg[it] >> 8], 1);
  }
  __syncthreads();
  for (int t = tid; t < KBUCKET; t += 256)
    base[t] = atomicAdd(&bucket_cnt[t], cnt[t]);
  __syncthreads();
  #pragma unroll
  for (int it = 0; it < 8; it++) {
    int i = it*256 + tid;
    if (i < EPB) {
      int s = src[e0 + i], d = dreg[it];
      int b = d >> 8;
      int r = atomicAdd(&cur[b], 1);
      bucketdata[(size_t)b * BCAP + base[b] + r] = ((uint)s << 8) | (uint)(d & 255);
    }
  }
}

// ---------------- W fragment prep (fp16) + bucket_cnt zeroing ----------------
__global__ __launch_bounds__(64) void prep_w(
    const float* __restrict__ Wl1, const float* __restrict__ Wr1,
    const float* __restrict__ Wl2, const float* __restrict__ Wr2,
    _Float16* __restrict__ wb, int* __restrict__ bucket_cnt)
{
  int bid = blockIdx.x;            // 2 layers * 4 C * 16 g = 128 blocks
  if (bid == 0) {
    for (int t = threadIdx.x; t < KBUCKET; t += 64) bucket_cnt[t] = 0;
  }
  int layer = bid >> 6, rest = bid & 63;
  int C = rest >> 4, g = rest & 15;
  int lane = threadIdx.x;
  int m = lane & 15, q = lane >> 4;
  int dim = g*16 + m;
  const float* W = layer ? (dim < 128 ? Wl2 : Wr2) : (dim < 128 ? Wl1 : Wr1);
  int dcol = dim & 127;
  _Float16 h[8];
  #pragma unroll
  for (int j = 0; j < 8; j++) {
    int k = C*32 + q*8 + j;
    h[j] = (_Float16)W[(size_t)k*DIM + dcol];
  }
  size_t off = ((size_t)bid*64 + lane)*8;
  *(hfrag8*)(wb + off) = *(hfrag8*)h;
}

// ---------------- merged: gemm layer1 (fp32 in) + CSR phase B + deg-sort ----
// blocks [0, KBUCKET): bucket_csr + per-bucket degree counting-sort -> perm.
// blocks [KBUCKET, ...): MFMA gemm. CSR/sort work hides under the GEMM.
// csr_soff stores src*256 (byte offset of the fp16 row) -- (p & ~255) is free.
__global__ __launch_bounds__(256) void gemm1_csr_k(
    const float* __restrict__ x, const _Float16* __restrict__ wb,
    const float* __restrict__ bl, const float* __restrict__ br,
    __half* __restrict__ xlh, __half* __restrict__ xrh,
    const int* __restrict__ bucket_cnt, const uint* __restrict__ bucketdata,
    int* __restrict__ row_start, int* __restrict__ csr_soff,
    int* __restrict__ perm)
{
  __shared__ float lds[4][16*LROW2];   // 33.8 KB (gemm path)
  __shared__ int hist[256], cur[256];  // csr path
  __shared__ int wsumA[4], wsumB[4];
  __shared__ int dhist[64], dbase[64], dcur[64];
  int tid = threadIdx.x;

  if (blockIdx.x < KBUCKET) {
    // ---- bucket_csr + degree-sort path ----
    int b = blockIdx.x;
    int lane = tid & 63, w = tid >> 6;
    int vv = (tid < b) ? bucket_cnt[tid] : 0;
    #pragma unroll
    for (int off = 32; off > 0; off >>= 1) vv += __shfl_xor(vv, off, 64);
    if (lane == 0) wsumA[w] = vv;
    hist[tid] = 0;
    if (tid < 64) { dhist[tid] = 0; dcur[tid] = 0; }
    __syncthreads();
    int base_csr = wsumA[0] + wsumA[1] + wsumA[2] + wsumA[3];
    int cnt = bucket_cnt[b];
    int node0 = b << 8;
    const uint* bd = bucketdata + (size_t)b * BCAP;
    for (int i = tid; i < cnt; i += 256)
      atomicAdd(&hist[bd[i] & 255], 1);
    __syncthreads();
    int v = hist[tid];
    int node = node0 + tid;
    int degc = (node < N_NODES) ? min(v, 63) : 63;   // invalids sort to end
    atomicAdd(&dhist[degc], 1);
    int inc = v;
    #pragma unroll
    for (int off = 1; off < 64; off <<= 1) {
      int y = __shfl_up(inc, off, 64);
      if (lane >= off) inc += y;
    }
    if (lane == 63) wsumB[w] = inc;
    __syncthreads();                                  // covers dhist too
    int wpre = 0;
    #pragma unroll
    for (int i = 0; i < 4; i++) if (i < w) wpre += wsumB[i];
    int excl = wpre + inc - v;
    if (node < N_NODES) row_start[node] = base_csr + excl;
    if (b == 0 && tid == 0) row_start[N_NODES] = N_EDGES;
    cur[tid] = excl;
    if (tid < 64) {                                   // exclusive scan of deg bins
      int c = dhist[tid];
      int ic = c;
      #pragma unroll
      for (int off = 1; off < 64; off <<= 1) {
        int y = __shfl_up(ic, off, 64);
        if (tid >= off) ic += y;
      }
      dbase[tid] = ic - c;
    }
    __syncthreads();
    int rank = dbase[degc] + atomicAdd(&dcur[degc], 1);
    perm[node0 + rank] = node;                        // value >= N marks invalid
    for (int i = tid; i < cnt; i += 256) {
      uint p = bd[i];
      int r = atomicAdd(&cur[p & 255], 1);
      csr_soff[base_csr + r] = (int)(p & 0xFFFFFF00u); // src*256 byte offset
    }
    return;
  }

  // ---- gemm path (layer 1, fp32 input) ----
  int wv = tid >> 6, lane = tid & 63;
  int G = (blockIdx.x - KBUCKET) * 4 + wv;
  if (G >= NGROUPS) return;

  int m = lane & 15, q = lane >> 4;
  const float* xrow = x + (size_t)(G*16 + m)*DIM + q*8;

  f32x4 acc[16];
  #pragma unroll
  for (int g = 0; g < 16; g++) acc[g] = (f32x4)(0.f);

  #pragma unroll 1
  for (int C = 0; C < 4; C++) {
    float v[8];
    *(float4*)(v)     = *(const float4*)(xrow + C*32);
    *(float4*)(v + 4) = *(const float4*)(xrow + C*32 + 4);
    _Float16 hh[8];
    #pragma unroll
    for (int j = 0; j < 8; j++) hh[j] = (_Float16)v[j];
    hfrag8 ah = *(hfrag8*)hh;
    #pragma unroll
    for (int g = 0; g < 16; g++) {
      size_t boff = ((size_t)(C*16 + g)*64 + lane)*8;
      hfrag8 bh = *(const hfrag8*)(wb + boff);
      acc[g] = __builtin_amdgcn_mfma_f32_16x16x32_f16(ah, bh, acc[g], 0, 0, 0);
    }
  }

  float* wlds = lds[wv];
  int dcol = (lane & 31) * 4;
  int rowsel = lane >> 5;
  #pragma unroll
  for (int half = 0; half < 2; half++) {
    #pragma unroll
    for (int g = 0; g < 8; g++) {
      #pragma unroll
      for (int r = 0; r < 4; r++)
        wlds[(q*4 + r)*LROW2 + g*16 + m] = acc[half*8 + g][r];
    }
    const float* B = half ? br : bl;
    ushort* outh = half ? (ushort*)xrh : (ushort*)xlh;
    float4 bv = *(const float4*)(B + dcol);
    #pragma unroll
    for (int it = 0; it < 8; it++) {
      int i = it*2 + rowsel;
      float4 vv2 = *(const float4*)(wlds + i*LROW2 + dcol);
      int node = G*16 + i;
      __half2 h0 = __floats2half2_rn(vv2.x + bv.x, vv2.y + bv.y);
      __half2 h1 = __floats2half2_rn(vv2.z + bv.z, vv2.w + bv.w);
      uint2 pk = make_uint2(*(uint*)&h0, *(uint*)&h1);
      *(uint2*)(outh + (size_t)node*DIM + dcol) = pk;
    }
  }
}

// ---------------- gather core: one node per 16-lane group --------------------
// csr_soff entries are byte offsets (src*256). Unroll 4, one-batch-ahead
// software pipeline, DPP row reduction (no DS shuffles).

#define GAT_LDI(OFF, TBASE)                                             \
  _Pragma("unroll")                                                     \
  for (int j = 0; j < 4; j++) {                                         \
    int rr = r0 + (TBASE) + j;                                          \
    OFF[j] = csr_soff[rr <= last ? rr : last];                          \
  }

#define GAT_LDR(OFF, RAW)                                               \
  _Pragma("unroll")                                                     \
  for (int j = 0; j < 4; j++)                                           \
    RAW[j] = *(const uint4*)(xb + (size_t)(uint)OFF[j]);

#define GAT_COMP(RAW, TBASE)                                            \
  _Pragma("unroll")                                                     \
  for (int j = 0; j < 4; j++) {                                         \
    h2 v01 = u2h(RAW[j].x), v23 = u2h(RAW[j].y);                        \
    h2 v45 = u2h(RAW[j].z), v67 = u2h(RAW[j].w);                        \
    h2 s01 = v01 + xr01, s23 = v23 + xr23;                              \
    h2 s45 = v45 + xr45, s67 = v67 + xr67;                              \
    s01 = __builtin_elementwise_max(s01, s01 * c02);                    \
    s23 = __builtin_elementwise_max(s23, s23 * c02);                    \
    s45 = __builtin_elementwise_max(s45, s45 * c02);                    \
    s67 = __builtin_elementwise_max(s67, s67 * c02);                    \
    float pA = __builtin_amdgcn_fdot2(s01, a01, 0.f, false);            \
    pA = __builtin_amdgcn_fdot2(s23, a23, pA, false);                   \
    float pB = __builtin_amdgcn_fdot2(s45, a45, 0.f, false);            \
    pB = __builtin_amdgcn_fdot2(s67, a67, pB, false);                   \
    float p = rowsum16(pA + pB);                                        \
    float w = ((TBASE) + j < deg) ? __expf(p) : 0.f;                    \
    l += w;                                                             \
    b0a = fmaf(w, (float)v01.x, b0a); b1a = fmaf(w, (float)v01.y, b1a); \
    b2a = fmaf(w, (float)v23.x, b2a); b3a = fmaf(w, (float)v23.y, b3a); \
    b4a = fmaf(w, (float)v45.x, b4a); b5a = fmaf(w, (float)v45.y, b5a); \
    b6a = fmaf(w, (float)v67.x, b6a); b7a = fmaf(w, (float)v67.y, b7a); \
  }

__device__ __forceinline__ void gather_core(
    int node, int valid, int hl,
    const __half* __restrict__ xlh, const __half* __restrict__ xrh,
    const int* __restrict__ row_start, const int* __restrict__ csr_soff,
    const float* __restrict__ att, const float* __restrict__ bias,
    float4& o0, float4& o1)
{
  int r0 = row_start[node];
  int deg = row_start[node + 1] - r0;
  if (!valid) deg = 0;
  int last = r0 + deg - 1;

  uint4 rx = *(const uint4*)((const ushort*)xrh + (size_t)node*DIM + hl*8);
  h2 xr01 = u2h(rx.x), xr23 = u2h(rx.y), xr45 = u2h(rx.z), xr67 = u2h(rx.w);
  const float* ap = att + hl*8;
  float4 af0 = *(const float4*)(ap);
  float4 af1 = *(const float4*)(ap + 4);
  h2 a01 = {(_Float16)af0.x, (_Float16)af0.y};
  h2 a23 = {(_Float16)af0.z, (_Float16)af0.w};
  h2 a45 = {(_Float16)af1.x, (_Float16)af1.y};
  h2 a67 = {(_Float16)af1.z, (_Float16)af1.w};
  const h2 c02 = {(_Float16)0.2f, (_Float16)0.2f};

  float l = 0.f;
  float b0a=0,b1a=0,b2a=0,b3a=0,b4a=0,b5a=0,b6a=0,b7a=0;
  const char* xb = (const char*)xlh + hl*16;

  int offA[4]; uint4 rawA[4];
  int offB[4]; uint4 rawB[4];

  if (deg > 0) { GAT_LDI(offA, 0); GAT_LDR(offA, rawA); }
  for (int t = 0; t < deg; t += 8) {
    bool hasB = (t + 4 < deg);
    if (hasB) { GAT_LDI(offB, t + 4); GAT_LDR(offB, rawB); }
    GAT_COMP(rawA, t);
    if (t + 8 < deg) { GAT_LDI(offA, t + 8); GAT_LDR(offA, rawA); }
    if (hasB) GAT_COMP(rawB, t + 4);
  }

  float inv = 1.f / fmaxf(l, 1e-16f);
  const float* bp = bias + hl*8;
  float4 c0 = *(const float4*)(bp);
  float4 c1 = *(const float4*)(bp + 4);
  o0.x = fmaxf(fmaf(b0a, inv, c0.x), 0.f);
  o0.y = fmaxf(fmaf(b1a, inv, c0.y), 0.f);
  o0.z = fmaxf(fmaf(b2a, inv, c0.z), 0.f);
  o0.w = fmaxf(fmaf(b3a, inv, c0.w), 0.f);
  o1.x = fmaxf(fmaf(b4a, inv, c1.x), 0.f);
  o1.y = fmaxf(fmaf(b5a, inv, c1.y), 0.f);
  o1.z = fmaxf(fmaf(b6a, inv, c1.z), 0.f);
  o1.w = fmaxf(fmaf(b7a, inv, c1.w), 0.f);
}

// ---------------- fused: gather layer1 + gemm layer2 -------------------------
// Block = 16 perm slots (4 waves x 4). Degree-sorted perm balances waves.
__global__ __launch_bounds__(256) void fused_g1_gemm2_k(
    const __half* __restrict__ xlh, const __half* __restrict__ xrh,
    const int* __restrict__ row_start, const int* __restrict__ csr_soff,
    const int* __restrict__ perm,
    const float* __restrict__ att, const float* __restrict__ bias,
    const _Float16* __restrict__ wb2,
    const float* __restrict__ bl2, const float* __restrict__ br2,
    __half* __restrict__ xlh2, __half* __restrict__ xrh2)
{
  __shared__ ushort xs[16*128];     // 4 KB: swizzled fp16 input rows
  __shared__ ushort outs[16*256];   // 8 KB: fp16 output rows (xl|xr)
  __shared__ int nodes_s[16];
  int tid = threadIdx.x;
  int wv = tid >> 6, lane = tid & 63;
  int q4 = lane >> 4, hl = lane & 15;
  int nl = wv*4 + q4;
  int base = blockIdx.x * 16;

  // ---- gather phase (layer 1) ----
  int node = perm[base + nl];
  int valid = node < N_NODES;
  int nodec = valid ? node : 0;
  if (hl == 0) nodes_s[nl] = node;   // node <= 50175 always (pad rows exist)
  float4 o0, o1;
  gather_core(nodec, valid, hl, xlh, xrh, row_start, csr_soff, att, bias, o0, o1);
  __half2 p0 = __floats2half2_rn(o0.x, o0.y);
  __half2 p1 = __floats2half2_rn(o0.z, o0.w);
  __half2 p2 = __floats2half2_rn(o1.x, o1.y);
  __half2 p3 = __floats2half2_rn(o1.z, o1.w);
  uint4 pk = make_uint4(*(uint*)&p0, *(uint*)&p1, *(uint*)&p2, *(uint*)&p3);
  *(uint4*)((char*)xs + nl*256 + ((hl*16) ^ ((nl&7)<<4))) = pk;
  __syncthreads();

  // ---- gemm phase (layer 2) ----
  int m = lane & 15, q = lane >> 4;
  f32x4 acc[4];
  #pragma unroll
  for (int g = 0; g < 4; g++) acc[g] = (f32x4)(0.f);
  #pragma unroll
  for (int C = 0; C < 4; C++) {
    hfrag8 ah = *(const hfrag8*)((const char*)xs + m*256 + ((C*64 + q*16) ^ ((m&7)<<4)));
    #pragma unroll
    for (int g = 0; g < 4; g++) {
      int gg = wv*4 + g;
      size_t boff = ((size_t)(C*16 + gg)*64 + lane)*8;
      hfrag8 bh = *(const hfrag8*)(wb2 + boff);
      acc[g] = __builtin_amdgcn_mfma_f32_16x16x32_f16(ah, bh, acc[g], 0, 0, 0);
    }
  }
  #pragma unroll
  for (int g = 0; g < 4; g++) {
    int gg = wv*4 + g;
    int dim = gg*16 + m;
    float bv = (gg < 8) ? bl2[dim] : br2[dim - 128];
    #pragma unroll
    for (int r = 0; r < 4; r++) {
      int row = q*4 + r;
      __half hv = __float2half_rn(acc[g][r] + bv);
      outs[row*256 + gg*16 + m] = *(ushort*)&hv;
    }
  }
  __syncthreads();
  #pragma unroll
  for (int p = 0; p < 2; p++) {
    int c = p*256 + tid;
    int row = c >> 5, off = c & 31;
    uint4 v = *(const uint4*)((const char*)outs + row*512 + off*16);
    int nodeo = nodes_s[row];        // may be a pad row (>= N_NODES): buffers padded
    int d0 = off*8;
    ushort* dstp = (d0 < 128) ? ((ushort*)xlh2 + (size_t)nodeo*DIM + d0)
                              : ((ushort*)xrh2 + (size_t)nodeo*DIM + (d0 - 128));
    *(uint4*)dstp = v;
  }
}

// ---------------- final gather (layer 2) -> fp32 output ----------------------
__global__ __launch_bounds__(256) void gat_gather2(
    const __half* __restrict__ xlh, const __half* __restrict__ xrh,
    const int* __restrict__ row_start, const int* __restrict__ csr_soff,
    const int* __restrict__ perm,
    const float* __restrict__ att, const float* __restrict__ bias,
    float* __restrict__ outf)
{
  int wave = (blockIdx.x * 256 + threadIdx.x) >> 6;
  int lane = threadIdx.x & 63;
  int q4 = lane >> 4;
  int hl = lane & 15;
  int slot = wave * 4 + q4;
  int node = perm[slot];
  int valid = node < N_NODES;
  int nodec = valid ? node : 0;
  float4 o0, o1;
  gather_core(nodec, valid, hl, xlh, xrh, row_start, csr_soff, att, bias, o0, o1);
  if (valid) {
    float* op = outf + (size_t)node*DIM + hl*8;
    *(float4*)(op)     = o0;
    *(float4*)(op + 4) = o1;
  }
}

extern "C" void kernel_launch(void* const* d_in, const int* in_sizes, int n_in,
                              void* d_out, int out_size, void* d_ws, size_t ws_size,
                              hipStream_t stream)
{
  const float* node_fts = (const float*)d_in[0];
  const int*  edge_index = (const int*)d_in[1];
  const float* Wl1 = (const float*)d_in[2];
  const float* bl1 = (const float*)d_in[3];
  const float* Wr1 = (const float*)d_in[4];
  const float* br1 = (const float*)d_in[5];
  const float* att1 = (const float*)d_in[6];
  const float* bias1 = (const float*)d_in[7];
  const float* Wl2 = (const float*)d_in[8];
  const float* bl2 = (const float*)d_in[9];
  const float* Wr2 = (const float*)d_in[10];
  const float* br2 = (const float*)d_in[11];
  const float* att2 = (const float*)d_in[12];
  const float* bias2 = (const float*)d_in[13];
  const int* src = edge_index;
  const int* dst = edge_index + N_EDGES;

  char* ws = (char*)d_ws;
  __half* xlh = (__half*)ws;               ws += (size_t)N_NODES*DIM*2;
  __half* xrh = (__half*)ws;               ws += (size_t)N_NODES*DIM*2;
  __half* xlh2 = (__half*)ws;              ws += (size_t)NSLOT*DIM*2;   // padded
  __half* xrh2 = (__half*)ws;              ws += (size_t)NSLOT*DIM*2;   // padded
  _Float16* wb = (_Float16*)ws;            ws += 2*4*16*64*8*2;
  int* row_start   = (int*)ws;             ws += (N_NODES+1)*4;
  int* csr_soff    = (int*)ws;             ws += (size_t)N_EDGES*4;
  int* perm        = (int*)ws;             ws += (size_t)NSLOT*4;
  int* bucket_cnt  = (int*)ws;             ws += KBUCKET*4;
  uint* bucketdata = (uint*)ws;            ws += (size_t)KBUCKET*BCAP*4;

  const int W_LAYER = 4*16*64*8;           // fp16 elems per layer of wb

  int gemm_blocks = (NGROUPS + 3) / 4;     // 782
  int slot_blocks = NSLOT / 16;            // 3136

  // L1: W frags + zero bucket_cnt
  prep_w<<<128, 64, 0, stream>>>(Wl1, Wr1, Wl2, Wr2, wb, bucket_cnt);
  // L2: CSR phase A
  bucket_scatter_k<<<N_EDGES/EPB, 256, 0, stream>>>(src, dst, bucket_cnt, bucketdata);
  // L3: gemm layer1 + CSR phase B + degree-sort perm (merged)
  gemm1_csr_k<<<KBUCKET + gemm_blocks, 256, 0, stream>>>(
      node_fts, wb, bl1, br1, xlh, xrh,
      bucket_cnt, bucketdata, row_start, csr_soff, perm);
  // L4: gather layer1 + gemm layer2 fused (degree-balanced)
  fused_g1_gemm2_k<<<slot_blocks, 256, 0, stream>>>(
      xlh, xrh, row_start, csr_soff, perm, att1, bias1,
      wb + W_LAYER, bl2, br2, xlh2, xrh2);
  // L5: final gather layer2 -> fp32 out (degree-balanced)
  gat_gather2<<<slot_blocks, 256, 0, stream>>>(
      xlh2, xrh2, row_start, csr_soff, perm, att2, bias2, (float*)d_out);
}

// Round 4
// 228.779 us; speedup vs baseline: 1.0050x; 1.0050x over previous
//
#include <hip/hip_runtime.h>
#include <hip/hip_bf16.h>
#include <hip/hip_fp16.h>

#define N_NODES 50000
#define N_EDGES 800000
#define DIM 128
#define NGROUPS (N_NODES / 16)                 // 3125 (exact)
#define LROW2 132                              // LDS row stride (floats)
#define KBUCKET 196                            // buckets of 256 nodes (dst>>8)
#define BCAP 5120                              // bucket capacity (mean 4096, ~16 sigma)
#define EPB 2000                               // edges per phase-A block (400 blocks)

typedef __attribute__((ext_vector_type(8))) _Float16 hfrag8;
typedef __attribute__((ext_vector_type(4))) float f32x4;
typedef _Float16 h2 __attribute__((ext_vector_type(2)));

__device__ __forceinline__ h2 u2h(uint u){ union{uint u; h2 h;} c; c.u = u; return c.h; }

// sum across the 16 lanes of a DPP row; all 16 lanes receive the total.
// row_ror:{8,4,2,1} circulant reduction -- pure VALU, no DS pipe.
__device__ __forceinline__ float rowsum16(float p) {
  union { float f; int i; } a, b;
  a.f = p;
  b.i = __builtin_amdgcn_update_dpp(0, a.i, 0x128, 0xF, 0xF, true); a.f += b.f;
  b.i = __builtin_amdgcn_update_dpp(0, a.i, 0x124, 0xF, 0xF, true); a.f += b.f;
  b.i = __builtin_amdgcn_update_dpp(0, a.i, 0x122, 0xF, 0xF, true); a.f += b.f;
  b.i = __builtin_amdgcn_update_dpp(0, a.i, 0x121, 0xF, 0xF, true); a.f += b.f;
  return a.f;
}

// ---------------- CSR build phase A: bucket scatter ----------------
// bucketdata entry packed: (src << 8) | (dst & 255)

__global__ __launch_bounds__(256) void bucket_scatter_k(
    const int* __restrict__ src, const int* __restrict__ dst,
    int* __restrict__ bucket_cnt, uint* __restrict__ bucketdata)
{
  __shared__ int cnt[KBUCKET], base[KBUCKET], cur[KBUCKET];
  int tid = threadIdx.x;
  for (int t = tid; t < KBUCKET; t += 256) { cnt[t] = 0; cur[t] = 0; }
  __syncthreads();
  int e0 = blockIdx.x * EPB;
  int dreg[8];                                 // cache dst: read once, use twice
  #pragma unroll
  for (int it = 0; it < 8; it++) {
    int i = it*256 + tid;
    dreg[it] = (i < EPB) ? dst[e0 + i] : -1;
    if (i < EPB) atomicAdd(&cnt[dreg[it] >> 8], 1);
  }
  __syncthreads();
  for (int t = tid; t < KBUCKET; t += 256)
    base[t] = atomicAdd(&bucket_cnt[t], cnt[t]);
  __syncthreads();
  #pragma unroll
  for (int it = 0; it < 8; it++) {
    int i = it*256 + tid;
    if (i < EPB) {
      int s = src[e0 + i], d = dreg[it];
      int b = d >> 8;
      int r = atomicAdd(&cur[b], 1);
      bucketdata[(size_t)b * BCAP + base[b] + r] = ((uint)s << 8) | (uint)(d & 255);
    }
  }
}

// ---------------- W fragment prep (fp16) + bucket_cnt zeroing ----------------
__global__ __launch_bounds__(64) void prep_w(
    const float* __restrict__ Wl1, const float* __restrict__ Wr1,
    const float* __restrict__ Wl2, const float* __restrict__ Wr2,
    _Float16* __restrict__ wb, int* __restrict__ bucket_cnt)
{
  int bid = blockIdx.x;            // 2 layers * 4 C * 16 g = 128 blocks
  if (bid == 0) {
    for (int t = threadIdx.x; t < KBUCKET; t += 64) bucket_cnt[t] = 0;
  }
  int layer = bid >> 6, rest = bid & 63;
  int C = rest >> 4, g = rest & 15;
  int lane = threadIdx.x;
  int m = lane & 15, q = lane >> 4;
  int dim = g*16 + m;
  const float* W = layer ? (dim < 128 ? Wl2 : Wr2) : (dim < 128 ? Wl1 : Wr1);
  int dcol = dim & 127;
  _Float16 h[8];
  #pragma unroll
  for (int j = 0; j < 8; j++) {
    int k = C*32 + q*8 + j;
    h[j] = (_Float16)W[(size_t)k*DIM + dcol];
  }
  size_t off = ((size_t)bid*64 + lane)*8;
  *(hfrag8*)(wb + off) = *(hfrag8*)h;
}

// ---------------- merged: gemm layer1 (fp32 in) + CSR phase B ----------------
// blocks [0, KBUCKET): bucket_csr. blocks [KBUCKET, ...): MFMA gemm.
// csr_soff stores src*256 (byte offset of the fp16 row).
__global__ __launch_bounds__(256) void gemm1_csr_k(
    const float* __restrict__ x, const _Float16* __restrict__ wb,
    const float* __restrict__ bl, const float* __restrict__ br,
    __half* __restrict__ xlh, __half* __restrict__ xrh,
    const int* __restrict__ bucket_cnt, const uint* __restrict__ bucketdata,
    int* __restrict__ row_start, int* __restrict__ csr_soff)
{
  __shared__ float lds[4][16*LROW2];   // 33.8 KB (gemm path)
  __shared__ int hist[256], cur[256];  // csr path
  __shared__ int wsumA[4], wsumB[4];
  int tid = threadIdx.x;

  if (blockIdx.x < KBUCKET) {
    // ---- bucket_csr path ----
    int b = blockIdx.x;
    int lane = tid & 63, w = tid >> 6;
    int vv = (tid < b) ? bucket_cnt[tid] : 0;
    #pragma unroll
    for (int off = 32; off > 0; off >>= 1) vv += __shfl_xor(vv, off, 64);
    if (lane == 0) wsumA[w] = vv;
    hist[tid] = 0;
    __syncthreads();
    int base_csr = wsumA[0] + wsumA[1] + wsumA[2] + wsumA[3];
    int cnt = bucket_cnt[b];
    int node0 = b << 8;
    const uint* bd = bucketdata + (size_t)b * BCAP;
    for (int i = tid; i < cnt; i += 256)
      atomicAdd(&hist[bd[i] & 255], 1);
    __syncthreads();
    int v = hist[tid];
    int inc = v;
    #pragma unroll
    for (int off = 1; off < 64; off <<= 1) {
      int y = __shfl_up(inc, off, 64);
      if (lane >= off) inc += y;
    }
    if (lane == 63) wsumB[w] = inc;
    __syncthreads();
    int wpre = 0;
    #pragma unroll
    for (int i = 0; i < 4; i++) if (i < w) wpre += wsumB[i];
    int excl = wpre + inc - v;
    int node = node0 + tid;
    if (node < N_NODES) row_start[node] = base_csr + excl;
    if (b == 0 && tid == 0) row_start[N_NODES] = N_EDGES;
    cur[tid] = excl;
    __syncthreads();
    for (int i = tid; i < cnt; i += 256) {
      uint p = bd[i];
      int r = atomicAdd(&cur[p & 255], 1);
      csr_soff[base_csr + r] = (int)(p & 0xFFFFFF00u);  // src*256 byte offset
    }
    return;
  }

  // ---- gemm path (layer 1, fp32 input) ----
  int wv = tid >> 6, lane = tid & 63;
  int G = (blockIdx.x - KBUCKET) * 4 + wv;
  if (G >= NGROUPS) return;

  int m = lane & 15, q = lane >> 4;
  const float* xrow = x + (size_t)(G*16 + m)*DIM + q*8;

  f32x4 acc[16];
  #pragma unroll
  for (int g = 0; g < 16; g++) acc[g] = (f32x4)(0.f);

  #pragma unroll 1
  for (int C = 0; C < 4; C++) {
    float v[8];
    *(float4*)(v)     = *(const float4*)(xrow + C*32);
    *(float4*)(v + 4) = *(const float4*)(xrow + C*32 + 4);
    _Float16 hh[8];
    #pragma unroll
    for (int j = 0; j < 8; j++) hh[j] = (_Float16)v[j];
    hfrag8 ah = *(hfrag8*)hh;
    #pragma unroll
    for (int g = 0; g < 16; g++) {
      size_t boff = ((size_t)(C*16 + g)*64 + lane)*8;
      hfrag8 bh = *(const hfrag8*)(wb + boff);
      acc[g] = __builtin_amdgcn_mfma_f32_16x16x32_f16(ah, bh, acc[g], 0, 0, 0);
    }
  }

  float* wlds = lds[wv];
  int dcol = (lane & 31) * 4;
  int rowsel = lane >> 5;
  #pragma unroll
  for (int half = 0; half < 2; half++) {
    #pragma unroll
    for (int g = 0; g < 8; g++) {
      #pragma unroll
      for (int r = 0; r < 4; r++)
        wlds[(q*4 + r)*LROW2 + g*16 + m] = acc[half*8 + g][r];
    }
    const float* B = half ? br : bl;
    ushort* outh = half ? (ushort*)xrh : (ushort*)xlh;
    float4 bv = *(const float4*)(B + dcol);
    #pragma unroll
    for (int it = 0; it < 8; it++) {
      int i = it*2 + rowsel;
      float4 vv2 = *(const float4*)(wlds + i*LROW2 + dcol);
      int node = G*16 + i;
      __half2 h0 = __floats2half2_rn(vv2.x + bv.x, vv2.y + bv.y);
      __half2 h1 = __floats2half2_rn(vv2.z + bv.z, vv2.w + bv.w);
      uint2 pk = make_uint2(*(uint*)&h0, *(uint*)&h1);
      *(uint2*)(outh + (size_t)node*DIM + dcol) = pk;
    }
  }
}

// ---------------- gather core: one node per 16-lane group --------------------
// csr_soff entries are byte offsets (src*256). Main loop = full batches of 4
// (no clamp, no deg-select), one-batch-ahead pipeline; single masked tail.
// att prescaled by log2e -> exp2f (1 trans op). DPP row reduction.

#define GAT_LDI4(OFF, RBASE)                                            \
  _Pragma("unroll")                                                     \
  for (int j = 0; j < 4; j++) OFF[j] = csr_soff[(RBASE) + j];

#define GAT_LDR4(OFF, RAW)                                              \
  _Pragma("unroll")                                                     \
  for (int j = 0; j < 4; j++)                                           \
    RAW[j] = *(const uint4*)(xb + (size_t)(uint)OFF[j]);

#define GAT_BODY(RAW, WEXPR)                                            \
  _Pragma("unroll")                                                     \
  for (int j = 0; j < 4; j++) {                                         \
    h2 v01 = u2h(RAW[j].x), v23 = u2h(RAW[j].y);                        \
    h2 v45 = u2h(RAW[j].z), v67 = u2h(RAW[j].w);                        \
    h2 s01 = v01 + xr01, s23 = v23 + xr23;                              \
    h2 s45 = v45 + xr45, s67 = v67 + xr67;                              \
    s01 = __builtin_elementwise_max(s01, s01 * c02);                    \
    s23 = __builtin_elementwise_max(s23, s23 * c02);                    \
    s45 = __builtin_elementwise_max(s45, s45 * c02);                    \
    s67 = __builtin_elementwise_max(s67, s67 * c02);                    \
    float pA = __builtin_amdgcn_fdot2(s01, a01, 0.f, false);            \
    pA = __builtin_amdgcn_fdot2(s23, a23, pA, false);                   \
    float pB = __builtin_amdgcn_fdot2(s45, a45, 0.f, false);            \
    pB = __builtin_amdgcn_fdot2(s67, a67, pB, false);                   \
    float p = rowsum16(pA + pB);                                        \
    float w = (WEXPR);                                                  \
    l += w;                                                             \
    b0a = fmaf(w, (float)v01.x, b0a); b1a = fmaf(w, (float)v01.y, b1a); \
    b2a = fmaf(w, (float)v23.x, b2a); b3a = fmaf(w, (float)v23.y, b3a); \
    b4a = fmaf(w, (float)v45.x, b4a); b5a = fmaf(w, (float)v45.y, b5a); \
    b6a = fmaf(w, (float)v67.x, b6a); b7a = fmaf(w, (float)v67.y, b7a); \
  }

__device__ __forceinline__ void gather_core(
    int node, int hl,
    const __half* __restrict__ xlh, const __half* __restrict__ xrh,
    const int* __restrict__ row_start, const int* __restrict__ csr_soff,
    const float* __restrict__ att, const float* __restrict__ bias,
    float4& o0, float4& o1)
{
  int r0 = row_start[node];
  int deg = row_start[node + 1] - r0;

  uint4 rx = *(const uint4*)((const ushort*)xrh + (size_t)node*DIM + hl*8);
  h2 xr01 = u2h(rx.x), xr23 = u2h(rx.y), xr45 = u2h(rx.z), xr67 = u2h(rx.w);
  const float* ap = att + hl*8;
  float4 af0 = *(const float4*)(ap);
  float4 af1 = *(const float4*)(ap + 4);
  const float L2E = 1.44269504088896f;       // exp(p) == exp2(p*log2e)
  h2 a01 = {(_Float16)(af0.x*L2E), (_Float16)(af0.y*L2E)};
  h2 a23 = {(_Float16)(af0.z*L2E), (_Float16)(af0.w*L2E)};
  h2 a45 = {(_Float16)(af1.x*L2E), (_Float16)(af1.y*L2E)};
  h2 a67 = {(_Float16)(af1.z*L2E), (_Float16)(af1.w*L2E)};
  const h2 c02 = {(_Float16)0.2f, (_Float16)0.2f};

  float l = 0.f;
  float b0a=0,b1a=0,b2a=0,b3a=0,b4a=0,b5a=0,b6a=0,b7a=0;
  const char* xb = (const char*)xlh + hl*16;

  int offA[4]; uint4 rawA[4];
  int offB[4]; uint4 rawB[4];
  int nfull = deg & ~3;

  if (nfull > 0) { GAT_LDI4(offA, r0); GAT_LDR4(offA, rawA); }
  #pragma unroll 1
  for (int t = 0; t < nfull; t += 8) {
    bool hasB = (t + 4 < nfull);
    if (hasB) { GAT_LDI4(offB, r0 + t + 4); GAT_LDR4(offB, rawB); }
    GAT_BODY(rawA, exp2f(p));
    if (t + 8 < nfull) { GAT_LDI4(offA, r0 + t + 8); GAT_LDR4(offA, rawA); }
    if (hasB) GAT_BODY(rawB, exp2f(p));
  }
  int rem = deg - nfull;
  if (rem > 0) {                             // masked tail batch (1..3 edges)
    #pragma unroll
    for (int j = 0; j < 4; j++) {
      int rr = r0 + nfull + (j < rem ? j : rem - 1);
      offA[j] = csr_soff[rr];
    }
    GAT_LDR4(offA, rawA);
    GAT_BODY(rawA, (j < rem) ? exp2f(p) : 0.f);
  }

  float inv = 1.f / fmaxf(l, 1e-16f);
  const float* bp = bias + hl*8;
  float4 c0 = *(const float4*)(bp);
  float4 c1 = *(const float4*)(bp + 4);
  o0.x = fmaxf(fmaf(b0a, inv, c0.x), 0.f);
  o0.y = fmaxf(fmaf(b1a, inv, c0.y), 0.f);
  o0.z = fmaxf(fmaf(b2a, inv, c0.z), 0.f);
  o0.w = fmaxf(fmaf(b3a, inv, c0.w), 0.f);
  o1.x = fmaxf(fmaf(b4a, inv, c1.x), 0.f);
  o1.y = fmaxf(fmaf(b5a, inv, c1.y), 0.f);
  o1.z = fmaxf(fmaf(b6a, inv, c1.z), 0.f);
  o1.w = fmaxf(fmaf(b7a, inv, c1.w), 0.f);
}

// ---------------- fused: gather layer1 + gemm layer2, wave-private -----------
// Block = 1 wave = 16 nodes. 4 gather rounds (4 nodes each) -> swizzled LDS;
// A-frags hoisted to registers; MFMA in 2 halves of 8 g-tiles; the single
// 4.2 KB LDS buffer is then reused for the fp16 transpose epilogue.
// No __syncthreads anywhere (wave-internal ordering only).
__global__ __launch_bounds__(64, 4) void fused_g1_gemm2_k(
    const __half* __restrict__ xlh, const __half* __restrict__ xrh,
    const int* __restrict__ row_start, const int* __restrict__ csr_soff,
    const float* __restrict__ att, const float* __restrict__ bias,
    const _Float16* __restrict__ wb2,
    const float* __restrict__ bl2, const float* __restrict__ br2,
    __half* __restrict__ xlh2, __half* __restrict__ xrh2)
{
  __shared__ ushort xs[16*132];   // 4224 B; rows stride 264 B (66 dw -> +2 banks)
  int lane = threadIdx.x;
  int q4 = lane >> 4, hl = lane & 15;
  int base = blockIdx.x * 16;     // 3125 * 16 = 50000 exact

  // ---- gather phase: 4 rounds x 4 nodes ----
  #pragma unroll 1
  for (int rr = 0; rr < 4; rr++) {
    int nl = rr*4 + q4;
    float4 o0, o1;
    gather_core(base + nl, hl, xlh, xrh, row_start, csr_soff, att, bias, o0, o1);
    __half2 p0 = __floats2half2_rn(o0.x, o0.y);
    __half2 p1 = __floats2half2_rn(o0.z, o0.w);
    __half2 p2 = __floats2half2_rn(o1.x, o1.y);
    __half2 p3 = __floats2half2_rn(o1.z, o1.w);
    uint4 pk = make_uint4(*(uint*)&p0, *(uint*)&p1, *(uint*)&p2, *(uint*)&p3);
    *(uint4*)((char*)xs + nl*264 + ((hl*16) ^ ((nl&7)<<4))) = pk;
  }

  // ---- hoist A-frags to registers (xs gets reused by the epilogue) ----
  hfrag8 ah[4];
  #pragma unroll
  for (int C = 0; C < 4; C++)
    ah[C] = *(const hfrag8*)((const char*)xs + hl*264 +
                             ((C*64 + q4*16) ^ ((hl&7)<<4)));

  // ---- gemm phase: 2 halves x 8 g-tiles x 4 C ----
  #pragma unroll 1
  for (int half = 0; half < 2; half++) {
    f32x4 acc[8];
    #pragma unroll
    for (int g = 0; g < 8; g++) acc[g] = (f32x4)(0.f);
    #pragma unroll
    for (int C = 0; C < 4; C++) {
      #pragma unroll
      for (int g = 0; g < 8; g++) {
        int gg = half*8 + g;
        hfrag8 bh = *(const hfrag8*)(wb2 + ((size_t)(C*16 + gg)*64 + lane)*8);
        acc[g] = __builtin_amdgcn_mfma_f32_16x16x32_f16(ah[C], bh, acc[g], 0, 0, 0);
      }
    }
    // epilogue: bias in f32, RNE cvt, transpose through reused xs.
    // write addr: rows (q4*4+r) 8 banks apart, m*2B 2-way dword share (free).
    const float* B = half ? br2 : bl2;
    #pragma unroll
    for (int g = 0; g < 8; g++) {
      float bv = B[g*16 + hl];
      #pragma unroll
      for (int r = 0; r < 4; r++) {
        __half hv = __float2half_rn(acc[g][r] + bv);
        xs[(q4*4 + r)*132 + g*16 + hl] = *(ushort*)&hv;
      }
    }
    // coalesced writeout: 16 rows x 128 fp16; 4 node-rows x 16 chunks / instr
    __half* dsth = half ? xrh2 : xlh2;
    #pragma unroll
    for (int i = 0; i < 4; i++) {
      int row = i*4 + q4;
      uint4 v = *(const uint4*)((const char*)xs + row*264 + hl*16);
      *(uint4*)((ushort*)dsth + (size_t)(base + row)*DIM + hl*8) = v;
    }
  }
}

// ---------------- final gather (layer 2) -> fp32 output ----------------------
__global__ __launch_bounds__(256) void gat_gather2(
    const __half* __restrict__ xlh, const __half* __restrict__ xrh,
    const int* __restrict__ row_start, const int* __restrict__ csr_soff,
    const float* __restrict__ att, const float* __restrict__ bias,
    float* __restrict__ outf)
{
  int wave = (blockIdx.x * 256 + threadIdx.x) >> 6;
  int lane = threadIdx.x & 63;
  int q4 = lane >> 4;
  int hl = lane & 15;
  int node = wave * 4 + q4;                  // 12500 waves * 4 = 50000 exact
  float4 o0, o1;
  gather_core(node, hl, xlh, xrh, row_start, csr_soff, att, bias, o0, o1);
  float* op = outf + (size_t)node*DIM + hl*8;
  *(float4*)(op)     = o0;
  *(float4*)(op + 4) = o1;
}

extern "C" void kernel_launch(void* const* d_in, const int* in_sizes, int n_in,
                              void* d_out, int out_size, void* d_ws, size_t ws_size,
                              hipStream_t stream)
{
  const float* node_fts = (const float*)d_in[0];
  const int*  edge_index = (const int*)d_in[1];
  const float* Wl1 = (const float*)d_in[2];
  const float* bl1 = (const float*)d_in[3];
  const float* Wr1 = (const float*)d_in[4];
  const float* br1 = (const float*)d_in[5];
  const float* att1 = (const float*)d_in[6];
  const float* bias1 = (const float*)d_in[7];
  const float* Wl2 = (const float*)d_in[8];
  const float* bl2 = (const float*)d_in[9];
  const float* Wr2 = (const float*)d_in[10];
  const float* br2 = (const float*)d_in[11];
  const float* att2 = (const float*)d_in[12];
  const float* bias2 = (const float*)d_in[13];
  const int* src = edge_index;
  const int* dst = edge_index + N_EDGES;

  char* ws = (char*)d_ws;
  __half* xlh = (__half*)ws;               ws += (size_t)N_NODES*DIM*2;
  __half* xrh = (__half*)ws;               ws += (size_t)N_NODES*DIM*2;
  __half* xlh2 = (__half*)ws;              ws += (size_t)N_NODES*DIM*2;
  __half* xrh2 = (__half*)ws;              ws += (size_t)N_NODES*DIM*2;
  _Float16* wb = (_Float16*)ws;            ws += 2*4*16*64*8*2;
  int* row_start   = (int*)ws;             ws += (N_NODES+1)*4;
  int* csr_soff    = (int*)ws;             ws += (size_t)N_EDGES*4;
  int* bucket_cnt  = (int*)ws;             ws += KBUCKET*4;
  uint* bucketdata = (uint*)ws;            ws += (size_t)KBUCKET*BCAP*4;

  const int W_LAYER = 4*16*64*8;           // fp16 elems per layer of wb

  int gemm_blocks = (NGROUPS + 3) / 4;     // 782
  int gather_blocks = N_NODES / 16;        // 3125 (256-thr blocks, 4 nodes/wave)

  // L1: W frags + zero bucket_cnt
  prep_w<<<128, 64, 0, stream>>>(Wl1, Wr1, Wl2, Wr2, wb, bucket_cnt);
  // L2: CSR phase A
  bucket_scatter_k<<<N_EDGES/EPB, 256, 0, stream>>>(src, dst, bucket_cnt, bucketdata);
  // L3: gemm layer1 + CSR phase B (merged; CSR hides under the GEMM)
  gemm1_csr_k<<<KBUCKET + gemm_blocks, 256, 0, stream>>>(
      node_fts, wb, bl1, br1, xlh, xrh,
      bucket_cnt, bucketdata, row_start, csr_soff);
  // L4: gather layer1 + gemm layer2 fused, wave-private (no barriers)
  fused_g1_gemm2_k<<<NGROUPS, 64, 0, stream>>>(
      xlh, xrh, row_start, csr_soff, att1, bias1,
      wb + W_LAYER, bl2, br2, xlh2, xrh2);
  // L5: final gather layer2 -> fp32 out
  gat_gather2<<<gather_blocks, 256, 0, stream>>>(
      xlh2, xrh2, row_start, csr_soff, att2, bias2, (float*)d_out);
}

// Round 5
// 220.580 us; speedup vs baseline: 1.0424x; 1.0372x over previous
//
#include <hip/hip_runtime.h>
#include <hip/hip_bf16.h>
#include <hip/hip_fp16.h>

#define N_NODES 50000
#define N_EDGES 800000
#define DIM 128
#define NGROUPS (N_NODES / 16)                 // 3125 (exact)
#define LROW2 132                              // LDS row stride (floats)
#define KBUCKET 196                            // buckets of 256 nodes (dst>>8)
#define BCAP 5120                              // bucket capacity (mean 4096, ~16 sigma)
#define EPB 2000                               // edges per phase-A block (400 blocks)
#define OSTR 260                               // outs row stride (ushorts): q-groups 8 banks apart

typedef __attribute__((ext_vector_type(8))) _Float16 hfrag8;
typedef __attribute__((ext_vector_type(4))) float f32x4;
typedef _Float16 h2 __attribute__((ext_vector_type(2)));

__device__ __forceinline__ h2 u2h(uint u){ union{uint u; h2 h;} c; c.u = u; return c.h; }

// sum across the 16 lanes of a DPP row; all 16 lanes receive the total.
__device__ __forceinline__ float rowsum16(float p) {
  union { float f; int i; } a, b;
  a.f = p;
  b.i = __builtin_amdgcn_update_dpp(0, a.i, 0x128, 0xF, 0xF, true); a.f += b.f;
  b.i = __builtin_amdgcn_update_dpp(0, a.i, 0x124, 0xF, 0xF, true); a.f += b.f;
  b.i = __builtin_amdgcn_update_dpp(0, a.i, 0x122, 0xF, 0xF, true); a.f += b.f;
  b.i = __builtin_amdgcn_update_dpp(0, a.i, 0x121, 0xF, 0xF, true); a.f += b.f;
  return a.f;
}

// ---------------- CSR build phase A: bucket scatter ----------------
// bucketdata entry packed: (src << 8) | (dst & 255)

__global__ __launch_bounds__(256) void bucket_scatter_k(
    const int* __restrict__ src, const int* __restrict__ dst,
    int* __restrict__ bucket_cnt, uint* __restrict__ bucketdata)
{
  __shared__ int cnt[KBUCKET], base[KBUCKET], cur[KBUCKET];
  int tid = threadIdx.x;
  for (int t = tid; t < KBUCKET; t += 256) { cnt[t] = 0; cur[t] = 0; }
  __syncthreads();
  int e0 = blockIdx.x * EPB;
  int dreg[8];                                 // cache dst: read once, use twice
  #pragma unroll
  for (int it = 0; it < 8; it++) {
    int i = it*256 + tid;
    dreg[it] = (i < EPB) ? dst[e0 + i] : -1;
    if (i < EPB) atomicAdd(&cnt[dreg[it] >> 8], 1);
  }
  __syncthreads();
  for (int t = tid; t < KBUCKET; t += 256)
    base[t] = atomicAdd(&bucket_cnt[t], cnt[t]);
  __syncthreads();
  #pragma unroll
  for (int it = 0; it < 8; it++) {
    int i = it*256 + tid;
    if (i < EPB) {
      int s = src[e0 + i], d = dreg[it];
      int b = d >> 8;
      int r = atomicAdd(&cur[b], 1);
      bucketdata[(size_t)b * BCAP + base[b] + r] = ((uint)s << 8) | (uint)(d & 255);
    }
  }
}

// ---------------- W fragment prep (fp16) + bucket_cnt zeroing ----------------
__global__ __launch_bounds__(64) void prep_w(
    const float* __restrict__ Wl1, const float* __restrict__ Wr1,
    const float* __restrict__ Wl2, const float* __restrict__ Wr2,
    _Float16* __restrict__ wb, int* __restrict__ bucket_cnt)
{
  int bid = blockIdx.x;            // 2 layers * 4 C * 16 g = 128 blocks
  if (bid == 0) {
    for (int t = threadIdx.x; t < KBUCKET; t += 64) bucket_cnt[t] = 0;
  }
  int layer = bid >> 6, rest = bid & 63;
  int C = rest >> 4, g = rest & 15;
  int lane = threadIdx.x;
  int m = lane & 15, q = lane >> 4;
  int dim = g*16 + m;
  const float* W = layer ? (dim < 128 ? Wl2 : Wr2) : (dim < 128 ? Wl1 : Wr1);
  int dcol = dim & 127;
  _Float16 h[8];
  #pragma unroll
  for (int j = 0; j < 8; j++) {
    int k = C*32 + q*8 + j;
    h[j] = (_Float16)W[(size_t)k*DIM + dcol];
  }
  size_t off = ((size_t)bid*64 + lane)*8;
  *(hfrag8*)(wb + off) = *(hfrag8*)h;
}

// ---------------- merged: gemm layer1 (fp32 in) + CSR phase B ----------------
__global__ __launch_bounds__(256) void gemm1_csr_k(
    const float* __restrict__ x, const _Float16* __restrict__ wb,
    const float* __restrict__ bl, const float* __restrict__ br,
    __half* __restrict__ xlh, __half* __restrict__ xrh,
    const int* __restrict__ bucket_cnt, const uint* __restrict__ bucketdata,
    int* __restrict__ row_start, int* __restrict__ csr_soff)
{
  __shared__ float lds[4][16*LROW2];   // 33.8 KB (gemm path)
  __shared__ int hist[256], cur[256];  // csr path
  __shared__ int wsumA[4], wsumB[4];
  int tid = threadIdx.x;

  if (blockIdx.x < KBUCKET) {
    // ---- bucket_csr path ----
    int b = blockIdx.x;
    int lane = tid & 63, w = tid >> 6;
    int vv = (tid < b) ? bucket_cnt[tid] : 0;
    #pragma unroll
    for (int off = 32; off > 0; off >>= 1) vv += __shfl_xor(vv, off, 64);
    if (lane == 0) wsumA[w] = vv;
    hist[tid] = 0;
    __syncthreads();
    int base_csr = wsumA[0] + wsumA[1] + wsumA[2] + wsumA[3];
    int cnt = bucket_cnt[b];
    int node0 = b << 8;
    const uint* bd = bucketdata + (size_t)b * BCAP;
    for (int i = tid; i < cnt; i += 256)
      atomicAdd(&hist[bd[i] & 255], 1);
    __syncthreads();
    int v = hist[tid];
    int inc = v;
    #pragma unroll
    for (int off = 1; off < 64; off <<= 1) {
      int y = __shfl_up(inc, off, 64);
      if (lane >= off) inc += y;
    }
    if (lane == 63) wsumB[w] = inc;
    __syncthreads();
    int wpre = 0;
    #pragma unroll
    for (int i = 0; i < 4; i++) if (i < w) wpre += wsumB[i];
    int excl = wpre + inc - v;
    int node = node0 + tid;
    if (node < N_NODES) row_start[node] = base_csr + excl;
    if (b == 0 && tid == 0) row_start[N_NODES] = N_EDGES;
    cur[tid] = excl;
    __syncthreads();
    for (int i = tid; i < cnt; i += 256) {
      uint p = bd[i];
      int r = atomicAdd(&cur[p & 255], 1);
      csr_soff[base_csr + r] = (int)(p & 0xFFFFFF00u);  // src*256 byte offset
    }
    return;
  }

  // ---- gemm path (layer 1, fp32 input) ----
  int wv = tid >> 6, lane = tid & 63;
  int G = (blockIdx.x - KBUCKET) * 4 + wv;
  if (G >= NGROUPS) return;

  int m = lane & 15, q = lane >> 4;
  const float* xrow = x + (size_t)(G*16 + m)*DIM + q*8;

  f32x4 acc[16];
  #pragma unroll
  for (int g = 0; g < 16; g++) acc[g] = (f32x4)(0.f);

  #pragma unroll 1
  for (int C = 0; C < 4; C++) {
    float v[8];
    *(float4*)(v)     = *(const float4*)(xrow + C*32);
    *(float4*)(v + 4) = *(const float4*)(xrow + C*32 + 4);
    _Float16 hh[8];
    #pragma unroll
    for (int j = 0; j < 8; j++) hh[j] = (_Float16)v[j];
    hfrag8 ah = *(hfrag8*)hh;
    #pragma unroll
    for (int g = 0; g < 16; g++) {
      size_t boff = ((size_t)(C*16 + g)*64 + lane)*8;
      hfrag8 bh = *(const hfrag8*)(wb + boff);
      acc[g] = __builtin_amdgcn_mfma_f32_16x16x32_f16(ah, bh, acc[g], 0, 0, 0);
    }
  }

  float* wlds = lds[wv];
  int dcol = (lane & 31) * 4;
  int rowsel = lane >> 5;
  #pragma unroll
  for (int half = 0; half < 2; half++) {
    #pragma unroll
    for (int g = 0; g < 8; g++) {
      #pragma unroll
      for (int r = 0; r < 4; r++)
        wlds[(q*4 + r)*LROW2 + g*16 + m] = acc[half*8 + g][r];
    }
    const float* B = half ? br : bl;
    ushort* outh = half ? (ushort*)xrh : (ushort*)xlh;
    float4 bv = *(const float4*)(B + dcol);
    #pragma unroll
    for (int it = 0; it < 8; it++) {
      int i = it*2 + rowsel;
      float4 vv2 = *(const float4*)(wlds + i*LROW2 + dcol);
      int node = G*16 + i;
      __half2 h0 = __floats2half2_rn(vv2.x + bv.x, vv2.y + bv.y);
      __half2 h1 = __floats2half2_rn(vv2.z + bv.z, vv2.w + bv.w);
      uint2 pk = make_uint2(*(uint*)&h0, *(uint*)&h1);
      *(uint2*)(outh + (size_t)node*DIM + dcol) = pk;
    }
  }
}

// ---------------- gather core: one node per 16-lane group --------------------
// csr_soff entries are byte offsets (src*256). Main loop = full batches of 4;
// DEEP=0: one-batch-ahead (A/B). DEEP=1: two-batch-ahead (A/B/C/D ping-pong,
// 16 edges in flight) for latency cover. Masked tail; exp2f; DPP reduction.

#define GAT_LDI4(OFF, RBASE)                                            \
  _Pragma("unroll")                                                     \
  for (int j = 0; j < 4; j++) OFF[j] = csr_soff[(RBASE) + j];

#define GAT_LDR4(OFF, RAW)                                              \
  _Pragma("unroll")                                                     \
  for (int j = 0; j < 4; j++)                                           \
    RAW[j] = *(const uint4*)(xb + (size_t)(uint)OFF[j]);

#define GAT_BODY(RAW, WEXPR)                                            \
  _Pragma("unroll")                                                     \
  for (int j = 0; j < 4; j++) {                                         \
    h2 v01 = u2h(RAW[j].x), v23 = u2h(RAW[j].y);                        \
    h2 v45 = u2h(RAW[j].z), v67 = u2h(RAW[j].w);                        \
    h2 s01 = v01 + xr01, s23 = v23 + xr23;                              \
    h2 s45 = v45 + xr45, s67 = v67 + xr67;                              \
    s01 = __builtin_elementwise_max(s01, s01 * c02);                    \
    s23 = __builtin_elementwise_max(s23, s23 * c02);                    \
    s45 = __builtin_elementwise_max(s45, s45 * c02);                    \
    s67 = __builtin_elementwise_max(s67, s67 * c02);                    \
    float pA = __builtin_amdgcn_fdot2(s01, a01, 0.f, false);            \
    pA = __builtin_amdgcn_fdot2(s23, a23, pA, false);                   \
    float pB = __builtin_amdgcn_fdot2(s45, a45, 0.f, false);            \
    pB = __builtin_amdgcn_fdot2(s67, a67, pB, false);                   \
    float p = rowsum16(pA + pB);                                        \
    float w = (WEXPR);                                                  \
    l += w;                                                             \
    b0a = fmaf(w, (float)v01.x, b0a); b1a = fmaf(w, (float)v01.y, b1a); \
    b2a = fmaf(w, (float)v23.x, b2a); b3a = fmaf(w, (float)v23.y, b3a); \
    b4a = fmaf(w, (float)v45.x, b4a); b5a = fmaf(w, (float)v45.y, b5a); \
    b6a = fmaf(w, (float)v67.x, b6a); b7a = fmaf(w, (float)v67.y, b7a); \
  }

template<int DEEP>
__device__ __forceinline__ void gather_core(
    int node, int hl,
    const __half* __restrict__ xlh, const __half* __restrict__ xrh,
    const int* __restrict__ row_start, const int* __restrict__ csr_soff,
    const float* __restrict__ att, const float* __restrict__ bias,
    float4& o0, float4& o1)
{
  int r0 = row_start[node];
  int deg = row_start[node + 1] - r0;

  uint4 rx = *(const uint4*)((const ushort*)xrh + (size_t)node*DIM + hl*8);
  h2 xr01 = u2h(rx.x), xr23 = u2h(rx.y), xr45 = u2h(rx.z), xr67 = u2h(rx.w);
  const float* ap = att + hl*8;
  float4 af0 = *(const float4*)(ap);
  float4 af1 = *(const float4*)(ap + 4);
  const float L2E = 1.44269504088896f;       // exp(p) == exp2(p*log2e)
  h2 a01 = {(_Float16)(af0.x*L2E), (_Float16)(af0.y*L2E)};
  h2 a23 = {(_Float16)(af0.z*L2E), (_Float16)(af0.w*L2E)};
  h2 a45 = {(_Float16)(af1.x*L2E), (_Float16)(af1.y*L2E)};
  h2 a67 = {(_Float16)(af1.z*L2E), (_Float16)(af1.w*L2E)};
  const h2 c02 = {(_Float16)0.2f, (_Float16)0.2f};

  float l = 0.f;
  float b0a=0,b1a=0,b2a=0,b3a=0,b4a=0,b5a=0,b6a=0,b7a=0;
  const char* xb = (const char*)xlh + hl*16;

  int offA[4]; uint4 rawA[4];
  int offB[4]; uint4 rawB[4];
  int nfull = deg & ~3;

  if constexpr (DEEP == 0) {
    if (nfull > 0) { GAT_LDI4(offA, r0); GAT_LDR4(offA, rawA); }
    #pragma unroll 1
    for (int t = 0; t < nfull; t += 8) {
      bool hasB = (t + 4 < nfull);
      if (hasB) { GAT_LDI4(offB, r0 + t + 4); GAT_LDR4(offB, rawB); }
      GAT_BODY(rawA, exp2f(p));
      if (t + 8 < nfull) { GAT_LDI4(offA, r0 + t + 8); GAT_LDR4(offA, rawA); }
      if (hasB) GAT_BODY(rawB, exp2f(p));
    }
  } else {
    int offC[4]; uint4 rawC[4];
    int offD[4]; uint4 rawD[4];
    if (nfull > 0) { GAT_LDI4(offA, r0);     GAT_LDR4(offA, rawA); }
    if (nfull > 4) { GAT_LDI4(offB, r0 + 4); GAT_LDR4(offB, rawB); }
    #pragma unroll 1
    for (int t = 0; t < nfull; t += 16) {
      if (t + 8  < nfull) { GAT_LDI4(offC, r0 + t + 8);  GAT_LDR4(offC, rawC); }
      GAT_BODY(rawA, exp2f(p));
      if (t + 12 < nfull) { GAT_LDI4(offD, r0 + t + 12); GAT_LDR4(offD, rawD); }
      if (t + 4  < nfull) GAT_BODY(rawB, exp2f(p));
      if (t + 16 < nfull) { GAT_LDI4(offA, r0 + t + 16); GAT_LDR4(offA, rawA); }
      if (t + 8  < nfull) GAT_BODY(rawC, exp2f(p));
      if (t + 20 < nfull) { GAT_LDI4(offB, r0 + t + 20); GAT_LDR4(offB, rawB); }
      if (t + 12 < nfull) GAT_BODY(rawD, exp2f(p));
    }
  }
  int rem = deg - nfull;
  if (rem > 0) {                             // masked tail batch (1..3 edges)
    #pragma unroll
    for (int j = 0; j < 4; j++) {
      int rr = r0 + nfull + (j < rem ? j : rem - 1);
      offA[j] = csr_soff[rr];
    }
    GAT_LDR4(offA, rawA);
    GAT_BODY(rawA, (j < rem) ? exp2f(p) : 0.f);
  }

  float inv = 1.f / fmaxf(l, 1e-16f);
  const float* bp = bias + hl*8;
  float4 c0 = *(const float4*)(bp);
  float4 c1 = *(const float4*)(bp + 4);
  o0.x = fmaxf(fmaf(b0a, inv, c0.x), 0.f);
  o0.y = fmaxf(fmaf(b1a, inv, c0.y), 0.f);
  o0.z = fmaxf(fmaf(b2a, inv, c0.z), 0.f);
  o0.w = fmaxf(fmaf(b3a, inv, c0.w), 0.f);
  o1.x = fmaxf(fmaf(b4a, inv, c1.x), 0.f);
  o1.y = fmaxf(fmaf(b5a, inv, c1.y), 0.f);
  o1.z = fmaxf(fmaf(b6a, inv, c1.z), 0.f);
  o1.w = fmaxf(fmaf(b7a, inv, c1.w), 0.f);
}

// ---------------- fused: gather layer1 + gemm layer2 -------------------------
// Block = 16 nodes (4 waves x 4 nodes each) -- the round-2 structure that
// measured best (occupancy), with the improved gather core and a
// conflict-free outs stride (260 ushorts: q-groups land 8 banks apart).
__global__ __launch_bounds__(256) void fused_g1_gemm2_k(
    const __half* __restrict__ xlh, const __half* __restrict__ xrh,
    const int* __restrict__ row_start, const int* __restrict__ csr_soff,
    const float* __restrict__ att, const float* __restrict__ bias,
    const _Float16* __restrict__ wb2,
    const float* __restrict__ bl2, const float* __restrict__ br2,
    __half* __restrict__ xlh2, __half* __restrict__ xrh2)
{
  __shared__ ushort xs[16*128];      // 4 KB: swizzled fp16 input rows
  __shared__ ushort outs[16*OSTR];   // 8.3 KB: fp16 output rows, padded stride
  int tid = threadIdx.x;
  int wv = tid >> 6, lane = tid & 63;
  int q4 = lane >> 4, hl = lane & 15;
  int nl = wv*4 + q4;
  int base = blockIdx.x * 16;        // 3125 * 16 = 50000 exact

  // ---- gather phase (layer 1) ----
  float4 o0, o1;
  gather_core<0>(base + nl, hl, xlh, xrh, row_start, csr_soff, att, bias, o0, o1);
  __half2 p0 = __floats2half2_rn(o0.x, o0.y);
  __half2 p1 = __floats2half2_rn(o0.z, o0.w);
  __half2 p2 = __floats2half2_rn(o1.x, o1.y);
  __half2 p3 = __floats2half2_rn(o1.z, o1.w);
  uint4 pk = make_uint4(*(uint*)&p0, *(uint*)&p1, *(uint*)&p2, *(uint*)&p3);
  // row nl, 16B chunk hl, XOR-swizzled so gemm's ds_read_b128 is conflict-free
  *(uint4*)((char*)xs + nl*256 + ((hl*16) ^ ((nl&7)<<4))) = pk;
  __syncthreads();

  // ---- gemm phase (layer 2) ----
  int m = lane & 15, q = lane >> 4;
  f32x4 acc[4];
  #pragma unroll
  for (int g = 0; g < 4; g++) acc[g] = (f32x4)(0.f);
  #pragma unroll
  for (int C = 0; C < 4; C++) {
    hfrag8 ah = *(const hfrag8*)((const char*)xs + m*256 + ((C*64 + q*16) ^ ((m&7)<<4)));
    #pragma unroll
    for (int g = 0; g < 4; g++) {
      int gg = wv*4 + g;
      size_t boff = ((size_t)(C*16 + gg)*64 + lane)*8;
      hfrag8 bh = *(const hfrag8*)(wb2 + boff);
      acc[g] = __builtin_amdgcn_mfma_f32_16x16x32_f16(ah, bh, acc[g], 0, 0, 0);
    }
  }
  // epilogue: bias in f32, RNE cvt, fp16 LDS transpose (conflict-free stride)
  #pragma unroll
  for (int g = 0; g < 4; g++) {
    int gg = wv*4 + g;
    int dim = gg*16 + m;
    float bv = (gg < 8) ? bl2[dim] : br2[dim - 128];
    #pragma unroll
    for (int r = 0; r < 4; r++) {
      int row = q*4 + r;
      __half hv = __float2half_rn(acc[g][r] + bv);
      outs[row*OSTR + gg*16 + m] = *(ushort*)&hv;
    }
  }
  __syncthreads();
  // cooperative coalesced writeout: 16 rows x 256 fp16
  #pragma unroll
  for (int p = 0; p < 2; p++) {
    int c = p*256 + tid;
    int row = c >> 5, off = c & 31;
    uint4 v = *(const uint4*)((const char*)outs + row*(OSTR*2) + off*16);
    int nodeo = base + row;
    int d0 = off*8;
    ushort* dstp = (d0 < 128) ? ((ushort*)xlh2 + (size_t)nodeo*DIM + d0)
                              : ((ushort*)xrh2 + (size_t)nodeo*DIM + (d0 - 128));
    *(uint4*)dstp = v;
  }
}

// ---------------- final gather (layer 2) -> fp32 output ----------------------
// DEEP=1: two-batch-ahead pipeline (16 edges in flight) -- latency experiment.
__global__ __launch_bounds__(256) void gat_gather2(
    const __half* __restrict__ xlh, const __half* __restrict__ xrh,
    const int* __restrict__ row_start, const int* __restrict__ csr_soff,
    const float* __restrict__ att, const float* __restrict__ bias,
    float* __restrict__ outf)
{
  int wave = (blockIdx.x * 256 + threadIdx.x) >> 6;
  int lane = threadIdx.x & 63;
  int q4 = lane >> 4;
  int hl = lane & 15;
  int node = wave * 4 + q4;                  // 12500 waves * 4 = 50000 exact
  float4 o0, o1;
  gather_core<1>(node, hl, xlh, xrh, row_start, csr_soff, att, bias, o0, o1);
  float* op = outf + (size_t)node*DIM + hl*8;
  *(float4*)(op)     = o0;
  *(float4*)(op + 4) = o1;
}

extern "C" void kernel_launch(void* const* d_in, const int* in_sizes, int n_in,
                              void* d_out, int out_size, void* d_ws, size_t ws_size,
                              hipStream_t stream)
{
  const float* node_fts = (const float*)d_in[0];
  const int*  edge_index = (const int*)d_in[1];
  const float* Wl1 = (const float*)d_in[2];
  const float* bl1 = (const float*)d_in[3];
  const float* Wr1 = (const float*)d_in[4];
  const float* br1 = (const float*)d_in[5];
  const float* att1 = (const float*)d_in[6];
  const float* bias1 = (const float*)d_in[7];
  const float* Wl2 = (const float*)d_in[8];
  const float* bl2 = (const float*)d_in[9];
  const float* Wr2 = (const float*)d_in[10];
  const float* br2 = (const float*)d_in[11];
  const float* att2 = (const float*)d_in[12];
  const float* bias2 = (const float*)d_in[13];
  const int* src = edge_index;
  const int* dst = edge_index + N_EDGES;

  char* ws = (char*)d_ws;
  __half* xlh = (__half*)ws;               ws += (size_t)N_NODES*DIM*2;
  __half* xrh = (__half*)ws;               ws += (size_t)N_NODES*DIM*2;
  __half* xlh2 = (__half*)ws;              ws += (size_t)N_NODES*DIM*2;
  __half* xrh2 = (__half*)ws;              ws += (size_t)N_NODES*DIM*2;
  _Float16* wb = (_Float16*)ws;            ws += 2*4*16*64*8*2;
  int* row_start   = (int*)ws;             ws += (N_NODES+1)*4;
  int* csr_soff    = (int*)ws;             ws += (size_t)N_EDGES*4;
  int* bucket_cnt  = (int*)ws;             ws += KBUCKET*4;
  uint* bucketdata = (uint*)ws;            ws += (size_t)KBUCKET*BCAP*4;

  const int W_LAYER = 4*16*64*8;           // fp16 elems per layer of wb

  int gemm_blocks = (NGROUPS + 3) / 4;     // 782
  int gather_blocks = N_NODES / 16;        // 3125

  // L1: W frags + zero bucket_cnt
  prep_w<<<128, 64, 0, stream>>>(Wl1, Wr1, Wl2, Wr2, wb, bucket_cnt);
  // L2: CSR phase A
  bucket_scatter_k<<<N_EDGES/EPB, 256, 0, stream>>>(src, dst, bucket_cnt, bucketdata);
  // L3: gemm layer1 + CSR phase B (merged; CSR hides under the GEMM)
  gemm1_csr_k<<<KBUCKET + gemm_blocks, 256, 0, stream>>>(
      node_fts, wb, bl1, br1, xlh, xrh,
      bucket_cnt, bucketdata, row_start, csr_soff);
  // L4: gather layer1 + gemm layer2 fused (4-wave blocks, barrier)
  fused_g1_gemm2_k<<<gather_blocks, 256, 0, stream>>>(
      xlh, xrh, row_start, csr_soff, att1, bias1,
      wb + W_LAYER, bl2, br2, xlh2, xrh2);
  // L5: final gather layer2 -> fp32 out (2-batch-ahead pipeline)
  gat_gather2<<<gather_blocks, 256, 0, stream>>>(
      xlh2, xrh2, row_start, csr_soff, att2, bias2, (float*)d_out);
}

// Round 6
// 217.769 us; speedup vs baseline: 1.0558x; 1.0129x over previous
//
#include <hip/hip_runtime.h>
#include <hip/hip_bf16.h>
#include <hip/hip_fp16.h>

#define N_NODES 50000
#define N_EDGES 800000
#define DIM 128
#define NGROUPS (N_NODES / 16)                 // 3125 (exact)
#define LROW2 132                              // LDS row stride (floats)
#define KBUCKET 196                            // buckets of 256 nodes (dst>>8)
#define BCAP 5120                              // bucket capacity (mean 4096, ~16 sigma)
#define EPB 2000                               // edges per phase-A block (400 blocks)
#define OSTR 260                               // outs row stride (ushorts)

typedef __attribute__((ext_vector_type(8))) _Float16 hfrag8;
typedef __attribute__((ext_vector_type(4))) float f32x4;
typedef _Float16 h2 __attribute__((ext_vector_type(2)));

__device__ __forceinline__ h2 u2h(uint u){ union{uint u; h2 h;} c; c.u = u; return c.h; }

// sum across the 16 lanes of a DPP row; all 16 lanes receive the total.
__device__ __forceinline__ float rowsum16(float p) {
  union { float f; int i; } a, b;
  a.f = p;
  b.i = __builtin_amdgcn_update_dpp(0, a.i, 0x128, 0xF, 0xF, true); a.f += b.f;
  b.i = __builtin_amdgcn_update_dpp(0, a.i, 0x124, 0xF, 0xF, true); a.f += b.f;
  b.i = __builtin_amdgcn_update_dpp(0, a.i, 0x122, 0xF, 0xF, true); a.f += b.f;
  b.i = __builtin_amdgcn_update_dpp(0, a.i, 0x121, 0xF, 0xF, true); a.f += b.f;
  return a.f;
}

// ---------------- CSR build phase A: bucket scatter ----------------
// bucketdata entry packed: (src << 8) | (dst & 255)

__global__ __launch_bounds__(256) void bucket_scatter_k(
    const int* __restrict__ src, const int* __restrict__ dst,
    int* __restrict__ bucket_cnt, uint* __restrict__ bucketdata)
{
  __shared__ int cnt[KBUCKET], base[KBUCKET], cur[KBUCKET];
  int tid = threadIdx.x;
  for (int t = tid; t < KBUCKET; t += 256) { cnt[t] = 0; cur[t] = 0; }
  __syncthreads();
  int e0 = blockIdx.x * EPB;
  int dreg[8];                                 // cache dst: read once, use twice
  #pragma unroll
  for (int it = 0; it < 8; it++) {
    int i = it*256 + tid;
    dreg[it] = (i < EPB) ? dst[e0 + i] : -1;
    if (i < EPB) atomicAdd(&cnt[dreg[it] >> 8], 1);
  }
  __syncthreads();
  for (int t = tid; t < KBUCKET; t += 256)
    base[t] = atomicAdd(&bucket_cnt[t], cnt[t]);
  __syncthreads();
  #pragma unroll
  for (int it = 0; it < 8; it++) {
    int i = it*256 + tid;
    if (i < EPB) {
      int s = src[e0 + i], d = dreg[it];
      int b = d >> 8;
      int r = atomicAdd(&cur[b], 1);
      bucketdata[(size_t)b * BCAP + base[b] + r] = ((uint)s << 8) | (uint)(d & 255);
    }
  }
}

// ---------------- W fragment prep (fp16) + bucket_cnt zeroing ----------------
__global__ __launch_bounds__(64) void prep_w(
    const float* __restrict__ Wl1, const float* __restrict__ Wr1,
    const float* __restrict__ Wl2, const float* __restrict__ Wr2,
    _Float16* __restrict__ wb, int* __restrict__ bucket_cnt)
{
  int bid = blockIdx.x;            // 2 layers * 4 C * 16 g = 128 blocks
  if (bid == 0) {
    for (int t = threadIdx.x; t < KBUCKET; t += 64) bucket_cnt[t] = 0;
  }
  int layer = bid >> 6, rest = bid & 63;
  int C = rest >> 4, g = rest & 15;
  int lane = threadIdx.x;
  int m = lane & 15, q = lane >> 4;
  int dim = g*16 + m;
  const float* W = layer ? (dim < 128 ? Wl2 : Wr2) : (dim < 128 ? Wl1 : Wr1);
  int dcol = dim & 127;
  _Float16 h[8];
  #pragma unroll
  for (int j = 0; j < 8; j++) {
    int k = C*32 + q*8 + j;
    h[j] = (_Float16)W[(size_t)k*DIM + dcol];
  }
  size_t off = ((size_t)bid*64 + lane)*8;
  *(hfrag8*)(wb + off) = *(hfrag8*)h;
}

// ---------------- merged: gemm layer1 (fp32 in) + CSR phase B ----------------
__global__ __launch_bounds__(256) void gemm1_csr_k(
    const float* __restrict__ x, const _Float16* __restrict__ wb,
    const float* __restrict__ bl, const float* __restrict__ br,
    __half* __restrict__ xlh, __half* __restrict__ xrh,
    const int* __restrict__ bucket_cnt, const uint* __restrict__ bucketdata,
    int* __restrict__ row_start, int* __restrict__ csr_soff)
{
  __shared__ float lds[4][16*LROW2];   // 33.8 KB (gemm path)
  __shared__ int hist[256], cur[256];  // csr path
  __shared__ int wsumA[4], wsumB[4];
  int tid = threadIdx.x;

  if (blockIdx.x < KBUCKET) {
    // ---- bucket_csr path ----
    int b = blockIdx.x;
    int lane = tid & 63, w = tid >> 6;
    int vv = (tid < b) ? bucket_cnt[tid] : 0;
    #pragma unroll
    for (int off = 32; off > 0; off >>= 1) vv += __shfl_xor(vv, off, 64);
    if (lane == 0) wsumA[w] = vv;
    hist[tid] = 0;
    __syncthreads();
    int base_csr = wsumA[0] + wsumA[1] + wsumA[2] + wsumA[3];
    int cnt = bucket_cnt[b];
    int node0 = b << 8;
    const uint* bd = bucketdata + (size_t)b * BCAP;
    for (int i = tid; i < cnt; i += 256)
      atomicAdd(&hist[bd[i] & 255], 1);
    __syncthreads();
    int v = hist[tid];
    int inc = v;
    #pragma unroll
    for (int off = 1; off < 64; off <<= 1) {
      int y = __shfl_up(inc, off, 64);
      if (lane >= off) inc += y;
    }
    if (lane == 63) wsumB[w] = inc;
    __syncthreads();
    int wpre = 0;
    #pragma unroll
    for (int i = 0; i < 4; i++) if (i < w) wpre += wsumB[i];
    int excl = wpre + inc - v;
    int node = node0 + tid;
    if (node < N_NODES) row_start[node] = base_csr + excl;
    if (b == 0 && tid == 0) row_start[N_NODES] = N_EDGES;
    cur[tid] = excl;
    __syncthreads();
    for (int i = tid; i < cnt; i += 256) {
      uint p = bd[i];
      int r = atomicAdd(&cur[p & 255], 1);
      csr_soff[base_csr + r] = (int)(p & 0xFFFFFF00u);  // src*256 byte offset
    }
    return;
  }

  // ---- gemm path (layer 1, fp32 input) ----
  int wv = tid >> 6, lane = tid & 63;
  int G = (blockIdx.x - KBUCKET) * 4 + wv;
  if (G >= NGROUPS) return;

  int m = lane & 15, q = lane >> 4;
  const float* xrow = x + (size_t)(G*16 + m)*DIM + q*8;

  f32x4 acc[16];
  #pragma unroll
  for (int g = 0; g < 16; g++) acc[g] = (f32x4)(0.f);

  #pragma unroll 1
  for (int C = 0; C < 4; C++) {
    float v[8];
    *(float4*)(v)     = *(const float4*)(xrow + C*32);
    *(float4*)(v + 4) = *(const float4*)(xrow + C*32 + 4);
    _Float16 hh[8];
    #pragma unroll
    for (int j = 0; j < 8; j++) hh[j] = (_Float16)v[j];
    hfrag8 ah = *(hfrag8*)hh;
    #pragma unroll
    for (int g = 0; g < 16; g++) {
      size_t boff = ((size_t)(C*16 + g)*64 + lane)*8;
      hfrag8 bh = *(const hfrag8*)(wb + boff);
      acc[g] = __builtin_amdgcn_mfma_f32_16x16x32_f16(ah, bh, acc[g], 0, 0, 0);
    }
  }

  float* wlds = lds[wv];
  int dcol = (lane & 31) * 4;
  int rowsel = lane >> 5;
  #pragma unroll
  for (int half = 0; half < 2; half++) {
    #pragma unroll
    for (int g = 0; g < 8; g++) {
      #pragma unroll
      for (int r = 0; r < 4; r++)
        wlds[(q*4 + r)*LROW2 + g*16 + m] = acc[half*8 + g][r];
    }
    const float* B = half ? br : bl;
    ushort* outh = half ? (ushort*)xrh : (ushort*)xlh;
    float4 bv = *(const float4*)(B + dcol);
    #pragma unroll
    for (int it = 0; it < 8; it++) {
      int i = it*2 + rowsel;
      float4 vv2 = *(const float4*)(wlds + i*LROW2 + dcol);
      int node = G*16 + i;
      __half2 h0 = __floats2half2_rn(vv2.x + bv.x, vv2.y + bv.y);
      __half2 h1 = __floats2half2_rn(vv2.z + bv.z, vv2.w + bv.w);
      uint2 pk = make_uint2(*(uint*)&h0, *(uint*)&h1);
      *(uint2*)(outh + (size_t)node*DIM + dcol) = pk;
    }
  }
}

// ---------------- gather core: one node per 16-lane group --------------------
// Index dependency removed from the loop: the first <=32 edge indices of each
// group are preloaded with 2 clamped lane-parallel loads, then batches get
// their 4 indices via ds_bpermute (DS pipe, ~50cy, overlapped) instead of a
// dependent VMEM load. Row loads then pipeline back-to-back. deg>32 tail
// (rare, Poisson-16) falls back to direct clamped loads (uniform branch).

#define GAT_IDX(OFF, TBASE)                                             \
  do {                                                                  \
    if ((TBASE) < 32) {                                                 \
      int _src = ((TBASE) < 16) ? my0 : my1;                            \
      _Pragma("unroll")                                                 \
      for (int j = 0; j < 4; j++)                                       \
        OFF[j] = __builtin_amdgcn_ds_bpermute(                          \
                     grpb4 + ((((TBASE) + j) & 15) << 2), _src);        \
    } else {                                                            \
      _Pragma("unroll")                                                 \
      for (int j = 0; j < 4; j++)                                       \
        OFF[j] = csr_soff[min(r0 + (TBASE) + j, last)];                 \
    }                                                                   \
  } while (0)

#define GAT_LDR4(OFF, RAW)                                              \
  _Pragma("unroll")                                                     \
  for (int j = 0; j < 4; j++)                                           \
    RAW[j] = *(const uint4*)(xb + (size_t)(uint)OFF[j]);

#define GAT_BODY(RAW, WEXPR)                                            \
  _Pragma("unroll")                                                     \
  for (int j = 0; j < 4; j++) {                                         \
    h2 v01 = u2h(RAW[j].x), v23 = u2h(RAW[j].y);                        \
    h2 v45 = u2h(RAW[j].z), v67 = u2h(RAW[j].w);                        \
    h2 s01 = v01 + xr01, s23 = v23 + xr23;                              \
    h2 s45 = v45 + xr45, s67 = v67 + xr67;                              \
    s01 = __builtin_elementwise_max(s01, s01 * c02);                    \
    s23 = __builtin_elementwise_max(s23, s23 * c02);                    \
    s45 = __builtin_elementwise_max(s45, s45 * c02);                    \
    s67 = __builtin_elementwise_max(s67, s67 * c02);                    \
    float pA = __builtin_amdgcn_fdot2(s01, a01, 0.f, false);            \
    pA = __builtin_amdgcn_fdot2(s23, a23, pA, false);                   \
    float pB = __builtin_amdgcn_fdot2(s45, a45, 0.f, false);            \
    pB = __builtin_amdgcn_fdot2(s67, a67, pB, false);                   \
    float p = rowsum16(pA + pB);                                        \
    float w = (WEXPR);                                                  \
    l += w;                                                             \
    b0a = fmaf(w, (float)v01.x, b0a); b1a = fmaf(w, (float)v01.y, b1a); \
    b2a = fmaf(w, (float)v23.x, b2a); b3a = fmaf(w, (float)v23.y, b3a); \
    b4a = fmaf(w, (float)v45.x, b4a); b5a = fmaf(w, (float)v45.y, b5a); \
    b6a = fmaf(w, (float)v67.x, b6a); b7a = fmaf(w, (float)v67.y, b7a); \
  }

__device__ __forceinline__ void gather_core(
    int node, int lane,
    const __half* __restrict__ xlh, const __half* __restrict__ xrh,
    const int* __restrict__ row_start, const int* __restrict__ csr_soff,
    const float* __restrict__ att, const float* __restrict__ bias,
    float4& o0, float4& o1)
{
  int hl = lane & 15;
  int grpb4 = (lane & 48) << 2;              // byte addr of group's lane 0
  int r0 = row_start[node];
  int deg = row_start[node + 1] - r0;
  int last = r0 + deg - 1;

  // preload first <=32 edge indices (clamped; masked off when deg==0)
  int my0 = 0, my1 = 0;
  if (deg > 0) {
    my0 = csr_soff[min(r0 + hl,      last)];
    my1 = csr_soff[min(r0 + 16 + hl, last)];
  }

  uint4 rx = *(const uint4*)((const ushort*)xrh + (size_t)node*DIM + hl*8);
  h2 xr01 = u2h(rx.x), xr23 = u2h(rx.y), xr45 = u2h(rx.z), xr67 = u2h(rx.w);
  const float* ap = att + hl*8;
  float4 af0 = *(const float4*)(ap);
  float4 af1 = *(const float4*)(ap + 4);
  const float L2E = 1.44269504088896f;       // exp(p) == exp2(p*log2e)
  h2 a01 = {(_Float16)(af0.x*L2E), (_Float16)(af0.y*L2E)};
  h2 a23 = {(_Float16)(af0.z*L2E), (_Float16)(af0.w*L2E)};
  h2 a45 = {(_Float16)(af1.x*L2E), (_Float16)(af1.y*L2E)};
  h2 a67 = {(_Float16)(af1.z*L2E), (_Float16)(af1.w*L2E)};
  const h2 c02 = {(_Float16)0.2f, (_Float16)0.2f};

  float l = 0.f;
  float b0a=0,b1a=0,b2a=0,b3a=0,b4a=0,b5a=0,b6a=0,b7a=0;
  const char* xb = (const char*)xlh + hl*16;

  int offA[4]; uint4 rawA[4];
  int offB[4]; uint4 rawB[4];
  int nfull = deg & ~3;

  if (nfull > 0) { GAT_IDX(offA, 0); GAT_LDR4(offA, rawA); }
  #pragma unroll 1
  for (int t = 0; t < nfull; t += 8) {
    bool hasB = (t + 4 < nfull);
    if (hasB) { GAT_IDX(offB, t + 4); GAT_LDR4(offB, rawB); }
    GAT_BODY(rawA, exp2f(p));
    if (t + 8 < nfull) { GAT_IDX(offA, t + 8); GAT_LDR4(offA, rawA); }
    if (hasB) GAT_BODY(rawB, exp2f(p));
  }
  int rem = deg - nfull;
  if (rem > 0) {                             // masked tail batch (1..3 edges)
    #pragma unroll
    for (int j = 0; j < 4; j++)
      offA[j] = csr_soff[min(r0 + nfull + j, last)];
    GAT_LDR4(offA, rawA);
    GAT_BODY(rawA, (j < rem) ? exp2f(p) : 0.f);
  }

  float inv = 1.f / fmaxf(l, 1e-16f);
  const float* bp = bias + hl*8;
  float4 c0 = *(const float4*)(bp);
  float4 c1 = *(const float4*)(bp + 4);
  o0.x = fmaxf(fmaf(b0a, inv, c0.x), 0.f);
  o0.y = fmaxf(fmaf(b1a, inv, c0.y), 0.f);
  o0.z = fmaxf(fmaf(b2a, inv, c0.z), 0.f);
  o0.w = fmaxf(fmaf(b3a, inv, c0.w), 0.f);
  o1.x = fmaxf(fmaf(b4a, inv, c1.x), 0.f);
  o1.y = fmaxf(fmaf(b5a, inv, c1.y), 0.f);
  o1.z = fmaxf(fmaf(b6a, inv, c1.z), 0.f);
  o1.w = fmaxf(fmaf(b7a, inv, c1.w), 0.f);
}

// ---------------- fused: gather layer1 + gemm layer2 -------------------------
// Block = 16 nodes (4 waves x 4 nodes each), one barrier, improved core.
__global__ __launch_bounds__(256) void fused_g1_gemm2_k(
    const __half* __restrict__ xlh, const __half* __restrict__ xrh,
    const int* __restrict__ row_start, const int* __restrict__ csr_soff,
    const float* __restrict__ att, const float* __restrict__ bias,
    const _Float16* __restrict__ wb2,
    const float* __restrict__ bl2, const float* __restrict__ br2,
    __half* __restrict__ xlh2, __half* __restrict__ xrh2)
{
  __shared__ ushort xs[16*128];      // 4 KB: swizzled fp16 input rows
  __shared__ ushort outs[16*OSTR];   // 8.3 KB: fp16 output rows, padded stride
  int tid = threadIdx.x;
  int wv = tid >> 6, lane = tid & 63;
  int q4 = lane >> 4, hl = lane & 15;
  int nl = wv*4 + q4;
  int base = blockIdx.x * 16;        // 3125 * 16 = 50000 exact

  // ---- gather phase (layer 1) ----
  float4 o0, o1;
  gather_core(base + nl, lane, xlh, xrh, row_start, csr_soff, att, bias, o0, o1);
  __half2 p0 = __floats2half2_rn(o0.x, o0.y);
  __half2 p1 = __floats2half2_rn(o0.z, o0.w);
  __half2 p2 = __floats2half2_rn(o1.x, o1.y);
  __half2 p3 = __floats2half2_rn(o1.z, o1.w);
  uint4 pk = make_uint4(*(uint*)&p0, *(uint*)&p1, *(uint*)&p2, *(uint*)&p3);
  // row nl, 16B chunk hl, XOR-swizzled so gemm's ds_read_b128 is conflict-free
  *(uint4*)((char*)xs + nl*256 + ((hl*16) ^ ((nl&7)<<4))) = pk;
  __syncthreads();

  // ---- gemm phase (layer 2) ----
  int m = lane & 15, q = lane >> 4;
  f32x4 acc[4];
  #pragma unroll
  for (int g = 0; g < 4; g++) acc[g] = (f32x4)(0.f);
  #pragma unroll
  for (int C = 0; C < 4; C++) {
    hfrag8 ah = *(const hfrag8*)((const char*)xs + m*256 + ((C*64 + q*16) ^ ((m&7)<<4)));
    #pragma unroll
    for (int g = 0; g < 4; g++) {
      int gg = wv*4 + g;
      size_t boff = ((size_t)(C*16 + gg)*64 + lane)*8;
      hfrag8 bh = *(const hfrag8*)(wb2 + boff);
      acc[g] = __builtin_amdgcn_mfma_f32_16x16x32_f16(ah, bh, acc[g], 0, 0, 0);
    }
  }
  // epilogue: bias in f32, RNE cvt, fp16 LDS transpose (padded stride)
  #pragma unroll
  for (int g = 0; g < 4; g++) {
    int gg = wv*4 + g;
    int dim = gg*16 + m;
    float bv = (gg < 8) ? bl2[dim] : br2[dim - 128];
    #pragma unroll
    for (int r = 0; r < 4; r++) {
      int row = q*4 + r;
      __half hv = __float2half_rn(acc[g][r] + bv);
      outs[row*OSTR + gg*16 + m] = *(ushort*)&hv;
    }
  }
  __syncthreads();
  // cooperative coalesced writeout: 16 rows x 256 fp16
  #pragma unroll
  for (int p = 0; p < 2; p++) {
    int c = p*256 + tid;
    int row = c >> 5, off = c & 31;
    uint4 v = *(const uint4*)((const char*)outs + row*(OSTR*2) + off*16);
    int nodeo = base + row;
    int d0 = off*8;
    ushort* dstp = (d0 < 128) ? ((ushort*)xlh2 + (size_t)nodeo*DIM + d0)
                              : ((ushort*)xrh2 + (size_t)nodeo*DIM + (d0 - 128));
    *(uint4*)dstp = v;
  }
}

// ---------------- final gather (layer 2) -> fp32 output ----------------------
__global__ __launch_bounds__(256) void gat_gather2(
    const __half* __restrict__ xlh, const __half* __restrict__ xrh,
    const int* __restrict__ row_start, const int* __restrict__ csr_soff,
    const float* __restrict__ att, const float* __restrict__ bias,
    float* __restrict__ outf)
{
  int wave = (blockIdx.x * 256 + threadIdx.x) >> 6;
  int lane = threadIdx.x & 63;
  int q4 = lane >> 4;
  int hl = lane & 15;
  int node = wave * 4 + q4;                  // 12500 waves * 4 = 50000 exact
  float4 o0, o1;
  gather_core(node, lane, xlh, xrh, row_start, csr_soff, att, bias, o0, o1);
  float* op = outf + (size_t)node*DIM + hl*8;
  *(float4*)(op)     = o0;
  *(float4*)(op + 4) = o1;
}

extern "C" void kernel_launch(void* const* d_in, const int* in_sizes, int n_in,
                              void* d_out, int out_size, void* d_ws, size_t ws_size,
                              hipStream_t stream)
{
  const float* node_fts = (const float*)d_in[0];
  const int*  edge_index = (const int*)d_in[1];
  const float* Wl1 = (const float*)d_in[2];
  const float* bl1 = (const float*)d_in[3];
  const float* Wr1 = (const float*)d_in[4];
  const float* br1 = (const float*)d_in[5];
  const float* att1 = (const float*)d_in[6];
  const float* bias1 = (const float*)d_in[7];
  const float* Wl2 = (const float*)d_in[8];
  const float* bl2 = (const float*)d_in[9];
  const float* Wr2 = (const float*)d_in[10];
  const float* br2 = (const float*)d_in[11];
  const float* att2 = (const float*)d_in[12];
  const float* bias2 = (const float*)d_in[13];
  const int* src = edge_index;
  const int* dst = edge_index + N_EDGES;

  char* ws = (char*)d_ws;
  __half* xlh = (__half*)ws;               ws += (size_t)N_NODES*DIM*2;
  __half* xrh = (__half*)ws;               ws += (size_t)N_NODES*DIM*2;
  __half* xlh2 = (__half*)ws;              ws += (size_t)N_NODES*DIM*2;
  __half* xrh2 = (__half*)ws;              ws += (size_t)N_NODES*DIM*2;
  _Float16* wb = (_Float16*)ws;            ws += 2*4*16*64*8*2;
  int* row_start   = (int*)ws;             ws += (N_NODES+1)*4;
  int* csr_soff    = (int*)ws;             ws += (size_t)N_EDGES*4;
  int* bucket_cnt  = (int*)ws;             ws += KBUCKET*4;
  uint* bucketdata = (uint*)ws;            ws += (size_t)KBUCKET*BCAP*4;

  const int W_LAYER = 4*16*64*8;           // fp16 elems per layer of wb

  int gemm_blocks = (NGROUPS + 3) / 4;     // 782
  int gather_blocks = N_NODES / 16;        // 3125

  // L1: W frags + zero bucket_cnt
  prep_w<<<128, 64, 0, stream>>>(Wl1, Wr1, Wl2, Wr2, wb, bucket_cnt);
  // L2: CSR phase A
  bucket_scatter_k<<<N_EDGES/EPB, 256, 0, stream>>>(src, dst, bucket_cnt, bucketdata);
  // L3: gemm layer1 + CSR phase B (merged; CSR hides under the GEMM)
  gemm1_csr_k<<<KBUCKET + gemm_blocks, 256, 0, stream>>>(
      node_fts, wb, bl1, br1, xlh, xrh,
      bucket_cnt, bucketdata, row_start, csr_soff);
  // L4: gather layer1 + gemm layer2 fused (4-wave blocks, barrier)
  fused_g1_gemm2_k<<<gather_blocks, 256, 0, stream>>>(
      xlh, xrh, row_start, csr_soff, att1, bias1,
      wb + W_LAYER, bl2, br2, xlh2, xrh2);
  // L5: final gather layer2 -> fp32 out (index-decoupled pipeline)
  gat_gather2<<<gather_blocks, 256, 0, stream>>>(
      xlh2, xrh2, row_start, csr_soff, att2, bias2, (float*)d_out);
}

// Round 8
// 214.738 us; speedup vs baseline: 1.0707x; 1.0141x over previous
//
#include <hip/hip_runtime.h>
#include <hip/hip_bf16.h>
#include <hip/hip_fp16.h>

#define N_NODES 50000
#define N_EDGES 800000
#define DIM 128
#define NGROUPS (N_NODES / 16)                 // 3125 (exact)
#define KBUCKET 196                            // buckets of 256 nodes (dst>>8)
#define BCAP 5120                              // bucket capacity (mean 4096, ~16 sigma)
#define EPB 2000                               // edges per phase-A block (400 blocks)
#define OSTR 260                               // fused outs row stride (ushorts)
#define TSTR 132                               // gemm1 fp16 transpose row stride (ushorts)

typedef __attribute__((ext_vector_type(8))) _Float16 hfrag8;
typedef __attribute__((ext_vector_type(4))) float f32x4;
typedef _Float16 h2 __attribute__((ext_vector_type(2)));

__device__ __forceinline__ h2 u2h(uint u){ union{uint u; h2 h;} c; c.u = u; return c.h; }

// sum across the 16 lanes of a DPP row; all 16 lanes receive the total.
__device__ __forceinline__ float rowsum16(float p) {
  union { float f; int i; } a, b;
  a.f = p;
  b.i = __builtin_amdgcn_update_dpp(0, a.i, 0x128, 0xF, 0xF, true); a.f += b.f;
  b.i = __builtin_amdgcn_update_dpp(0, a.i, 0x124, 0xF, 0xF, true); a.f += b.f;
  b.i = __builtin_amdgcn_update_dpp(0, a.i, 0x122, 0xF, 0xF, true); a.f += b.f;
  b.i = __builtin_amdgcn_update_dpp(0, a.i, 0x121, 0xF, 0xF, true); a.f += b.f;
  return a.f;
}

// ---------------- CSR build phase A: bucket scatter ----------------
// bucketdata entry packed: (src << 8) | (dst & 255)

__global__ __launch_bounds__(256) void bucket_scatter_k(
    const int* __restrict__ src, const int* __restrict__ dst,
    int* __restrict__ bucket_cnt, uint* __restrict__ bucketdata)
{
  __shared__ int cnt[KBUCKET], base[KBUCKET], cur[KBUCKET];
  int tid = threadIdx.x;
  for (int t = tid; t < KBUCKET; t += 256) { cnt[t] = 0; cur[t] = 0; }
  __syncthreads();
  int e0 = blockIdx.x * EPB;
  int dreg[8];                                 // cache dst: read once, use twice
  #pragma unroll
  for (int it = 0; it < 8; it++) {
    int i = it*256 + tid;
    dreg[it] = (i < EPB) ? dst[e0 + i] : -1;
    if (i < EPB) atomicAdd(&cnt[dreg[it] >> 8], 1);
  }
  __syncthreads();
  for (int t = tid; t < KBUCKET; t += 256)
    base[t] = atomicAdd(&bucket_cnt[t], cnt[t]);
  __syncthreads();
  #pragma unroll
  for (int it = 0; it < 8; it++) {
    int i = it*256 + tid;
    if (i < EPB) {
      int s = src[e0 + i], d = dreg[it];
      int b = d >> 8;
      int r = atomicAdd(&cur[b], 1);
      bucketdata[(size_t)b * BCAP + base[b] + r] = ((uint)s << 8) | (uint)(d & 255);
    }
  }
}

// ---------------- W fragment prep (fp16) + bucket_cnt zeroing ----------------
__global__ __launch_bounds__(64) void prep_w(
    const float* __restrict__ Wl1, const float* __restrict__ Wr1,
    const float* __restrict__ Wl2, const float* __restrict__ Wr2,
    _Float16* __restrict__ wb, int* __restrict__ bucket_cnt)
{
  int bid = blockIdx.x;            // 2 layers * 4 C * 16 g = 128 blocks
  if (bid == 0) {
    for (int t = threadIdx.x; t < KBUCKET; t += 64) bucket_cnt[t] = 0;
  }
  int layer = bid >> 6, rest = bid & 63;
  int C = rest >> 4, g = rest & 15;
  int lane = threadIdx.x;
  int m = lane & 15, q = lane >> 4;
  int dim = g*16 + m;
  const float* W = layer ? (dim < 128 ? Wl2 : Wr2) : (dim < 128 ? Wl1 : Wr1);
  int dcol = dim & 127;
  _Float16 h[8];
  #pragma unroll
  for (int j = 0; j < 8; j++) {
    int k = C*32 + q*8 + j;
    h[j] = (_Float16)W[(size_t)k*DIM + dcol];
  }
  size_t off = ((size_t)bid*64 + lane)*8;
  *(hfrag8*)(wb + off) = *(hfrag8*)h;
}

// ---------------- merged: gemm layer1 (fp32 in) + CSR phase B ----------------
// gemm path v2: wb C-chunks staged through LDS (1 copy per block instead of 4
// -> wb L2 traffic 200 MB -> 50 MB); fp16 per-wave transpose epilogue.
// Last-block guard is clamp+predicate (no early return: block-wide barriers).
__global__ __launch_bounds__(256) void gemm1_csr_k(
    const float* __restrict__ x, const _Float16* __restrict__ wb,
    const float* __restrict__ bl, const float* __restrict__ br,
    __half* __restrict__ xlh, __half* __restrict__ xrh,
    const int* __restrict__ bucket_cnt, const uint* __restrict__ bucketdata,
    int* __restrict__ row_start, int* __restrict__ csr_soff)
{
  __shared__ int hist[256], cur[256];        // csr path
  __shared__ int wsumA[4], wsumB[4];
  __shared__ _Float16 wstage[16*64*8];       // 16 KB: one wb C-chunk
  __shared__ ushort touts[4][16*TSTR];       // 16.9 KB: per-wave fp16 transpose
  int tid = threadIdx.x;

  if (blockIdx.x < KBUCKET) {
    // ---- bucket_csr path (unchanged) ----
    int b = blockIdx.x;
    int lane = tid & 63, w = tid >> 6;
    int vv = (tid < b) ? bucket_cnt[tid] : 0;
    #pragma unroll
    for (int off = 32; off > 0; off >>= 1) vv += __shfl_xor(vv, off, 64);
    if (lane == 0) wsumA[w] = vv;
    hist[tid] = 0;
    __syncthreads();
    int base_csr = wsumA[0] + wsumA[1] + wsumA[2] + wsumA[3];
    int cnt = bucket_cnt[b];
    int node0 = b << 8;
    const uint* bd = bucketdata + (size_t)b * BCAP;
    for (int i = tid; i < cnt; i += 256)
      atomicAdd(&hist[bd[i] & 255], 1);
    __syncthreads();
    int v = hist[tid];
    int inc = v;
    #pragma unroll
    for (int off = 1; off < 64; off <<= 1) {
      int y = __shfl_up(inc, off, 64);
      if (lane >= off) inc += y;
    }
    if (lane == 63) wsumB[w] = inc;
    __syncthreads();
    int wpre = 0;
    #pragma unroll
    for (int i = 0; i < 4; i++) if (i < w) wpre += wsumB[i];
    int excl = wpre + inc - v;
    int node = node0 + tid;
    if (node < N_NODES) row_start[node] = base_csr + excl;
    if (b == 0 && tid == 0) row_start[N_NODES] = N_EDGES;
    cur[tid] = excl;
    __syncthreads();
    for (int i = tid; i < cnt; i += 256) {
      uint p = bd[i];
      int r = atomicAdd(&cur[p & 255], 1);
      csr_soff[base_csr + r] = (int)(p & 0xFFFFFF00u);  // src*256 byte offset
    }
    return;
  }

  // ---- gemm path (layer 1, fp32 input), wb LDS-staged ----
  int wv = tid >> 6, lane = tid & 63;
  int G = (blockIdx.x - KBUCKET) * 4 + wv;
  bool wvalid = (G < NGROUPS);
  if (!wvalid) G = NGROUPS - 1;              // clamp: loads safe, writes guarded

  int m = lane & 15, q = lane >> 4;
  const float* xrow = x + (size_t)(G*16 + m)*DIM + q*8;

  f32x4 acc[16];
  #pragma unroll
  for (int g = 0; g < 16; g++) acc[g] = (f32x4)(0.f);

  #pragma unroll 1
  for (int C = 0; C < 4; C++) {
    __syncthreads();                         // wstage reuse from previous C
    {                                        // cooperative 16-KB chunk stage
      const uint4* srcw = (const uint4*)(wb + (size_t)C*16*64*8);
      uint4* dstw = (uint4*)wstage;
      #pragma unroll
      for (int k = 0; k < 4; k++)
        dstw[k*256 + tid] = srcw[k*256 + tid];
    }
    __syncthreads();
    float v[8];
    *(float4*)(v)     = *(const float4*)(xrow + C*32);
    *(float4*)(v + 4) = *(const float4*)(xrow + C*32 + 4);
    _Float16 hh[8];
    #pragma unroll
    for (int j = 0; j < 8; j++) hh[j] = (_Float16)v[j];
    hfrag8 ah = *(hfrag8*)hh;
    #pragma unroll
    for (int g = 0; g < 16; g++) {
      hfrag8 bh = *(const hfrag8*)(wstage + ((size_t)g*64 + lane)*8);
      acc[g] = __builtin_amdgcn_mfma_f32_16x16x32_f16(ah, bh, acc[g], 0, 0, 0);
    }
  }

  // epilogue: bias f32, RNE cvt, fp16 per-wave transpose (wave-internal order)
  ushort* tw = touts[wv];
  #pragma unroll
  for (int half = 0; half < 2; half++) {
    const float* B = half ? br : bl;
    ushort* outh = half ? (ushort*)xrh : (ushort*)xlh;
    #pragma unroll
    for (int g = 0; g < 8; g++) {
      float bv = B[g*16 + m];
      #pragma unroll
      for (int r = 0; r < 4; r++) {
        __half hv = __float2half_rn(acc[half*8 + g][r] + bv);
        tw[(q*4 + r)*TSTR + g*16 + m] = *(ushort*)&hv;
      }
    }
    // coalesced per-wave writeout: 16 rows x 128 fp16 = 256 x 16B chunks,
    // 4 iterations x 64 lanes (round-7 bug: 2 iters covered only dims 0..63)
    #pragma unroll
    for (int i = 0; i < 4; i++) {
      int c = i*64 + lane;
      int row = c >> 4, off = c & 15;
      uint4 vv = *(const uint4*)((const char*)tw + row*(TSTR*2) + off*16);
      if (wvalid)
        *(uint4*)(outh + (size_t)(G*16 + row)*DIM + off*8) = vv;
    }
  }
}

// ---------------- gather core: one node per 16-lane group --------------------
// Indices of the first <=32 edges preloaded lane-parallel (my1 only when
// needed), distributed per-batch via ds_bpermute; row loads pipeline A/B.
// exp2f via att prescaled by log2e; DPP row reduction; masked tail batch.

#define GAT_IDX(OFF, TBASE)                                             \
  do {                                                                  \
    if ((TBASE) < 32) {                                                 \
      int _src = ((TBASE) < 16) ? my0 : my1;                            \
      _Pragma("unroll")                                                 \
      for (int j = 0; j < 4; j++)                                       \
        OFF[j] = __builtin_amdgcn_ds_bpermute(                          \
                     grpb4 + ((((TBASE) + j) & 15) << 2), _src);        \
    } else {                                                            \
      _Pragma("unroll")                                                 \
      for (int j = 0; j < 4; j++)                                       \
        OFF[j] = csr_soff[min(r0 + (TBASE) + j, last)];                 \
    }                                                                   \
  } while (0)

#define GAT_LDR4(OFF, RAW)                                              \
  _Pragma("unroll")                                                     \
  for (int j = 0; j < 4; j++)                                           \
    RAW[j] = *(const uint4*)(xb + (size_t)(uint)OFF[j]);

#define GAT_BODY(RAW, WEXPR)                                            \
  _Pragma("unroll")                                                     \
  for (int j = 0; j < 4; j++) {                                         \
    h2 v01 = u2h(RAW[j].x), v23 = u2h(RAW[j].y);                        \
    h2 v45 = u2h(RAW[j].z), v67 = u2h(RAW[j].w);                        \
    h2 s01 = v01 + xr01, s23 = v23 + xr23;                              \
    h2 s45 = v45 + xr45, s67 = v67 + xr67;                              \
    s01 = __builtin_elementwise_max(s01, s01 * c02);                    \
    s23 = __builtin_elementwise_max(s23, s23 * c02);                    \
    s45 = __builtin_elementwise_max(s45, s45 * c02);                    \
    s67 = __builtin_elementwise_max(s67, s67 * c02);                    \
    float pA = __builtin_amdgcn_fdot2(s01, a01, 0.f, false);            \
    pA = __builtin_amdgcn_fdot2(s23, a23, pA, false);                   \
    float pB = __builtin_amdgcn_fdot2(s45, a45, 0.f, false);            \
    pB = __builtin_amdgcn_fdot2(s67, a67, pB, false);                   \
    float p = rowsum16(pA + pB);                                        \
    float w = (WEXPR);                                                  \
    l += w;                                                             \
    b0a = fmaf(w, (float)v01.x, b0a); b1a = fmaf(w, (float)v01.y, b1a); \
    b2a = fmaf(w, (float)v23.x, b2a); b3a = fmaf(w, (float)v23.y, b3a); \
    b4a = fmaf(w, (float)v45.x, b4a); b5a = fmaf(w, (float)v45.y, b5a); \
    b6a = fmaf(w, (float)v67.x, b6a); b7a = fmaf(w, (float)v67.y, b7a); \
  }

__device__ __forceinline__ void gather_core(
    int node, int lane,
    const __half* __restrict__ xlh, const __half* __restrict__ xrh,
    const int* __restrict__ row_start, const int* __restrict__ csr_soff,
    const float* __restrict__ att, const float* __restrict__ bias,
    float4& o0, float4& o1)
{
  int hl = lane & 15;
  int grpb4 = (lane & 48) << 2;              // byte addr of group's lane 0
  int r0 = row_start[node];
  int deg = row_start[node + 1] - r0;
  int last = r0 + deg - 1;

  // preload first <=32 edge indices (clamped; my1 only when batches need it)
  int my0 = 0, my1 = 0;
  if (deg > 0)  my0 = csr_soff[min(r0 + hl,      last)];
  if (deg > 16) my1 = csr_soff[min(r0 + 16 + hl, last)];

  uint4 rx = *(const uint4*)((const ushort*)xrh + (size_t)node*DIM + hl*8);
  h2 xr01 = u2h(rx.x), xr23 = u2h(rx.y), xr45 = u2h(rx.z), xr67 = u2h(rx.w);
  const float* ap = att + hl*8;
  float4 af0 = *(const float4*)(ap);
  float4 af1 = *(const float4*)(ap + 4);
  const float L2E = 1.44269504088896f;       // exp(p) == exp2(p*log2e)
  h2 a01 = {(_Float16)(af0.x*L2E), (_Float16)(af0.y*L2E)};
  h2 a23 = {(_Float16)(af0.z*L2E), (_Float16)(af0.w*L2E)};
  h2 a45 = {(_Float16)(af1.x*L2E), (_Float16)(af1.y*L2E)};
  h2 a67 = {(_Float16)(af1.z*L2E), (_Float16)(af1.w*L2E)};
  const h2 c02 = {(_Float16)0.2f, (_Float16)0.2f};

  float l = 0.f;
  float b0a=0,b1a=0,b2a=0,b3a=0,b4a=0,b5a=0,b6a=0,b7a=0;
  const char* xb = (const char*)xlh + hl*16;

  int offA[4]; uint4 rawA[4];
  int offB[4]; uint4 rawB[4];
  int nfull = deg & ~3;

  if (nfull > 0) { GAT_IDX(offA, 0); GAT_LDR4(offA, rawA); }
  #pragma unroll 1
  for (int t = 0; t < nfull; t += 8) {
    bool hasB = (t + 4 < nfull);
    if (hasB) { GAT_IDX(offB, t + 4); GAT_LDR4(offB, rawB); }
    GAT_BODY(rawA, exp2f(p));
    if (t + 8 < nfull) { GAT_IDX(offA, t + 8); GAT_LDR4(offA, rawA); }
    if (hasB) GAT_BODY(rawB, exp2f(p));
  }
  int rem = deg - nfull;
  if (rem > 0) {                             // masked tail batch (1..3 edges)
    #pragma unroll
    for (int j = 0; j < 4; j++)
      offA[j] = csr_soff[min(r0 + nfull + j, last)];
    GAT_LDR4(offA, rawA);
    GAT_BODY(rawA, (j < rem) ? exp2f(p) : 0.f);
  }

  float inv = 1.f / fmaxf(l, 1e-16f);
  const float* bp = bias + hl*8;
  float4 c0 = *(const float4*)(bp);
  float4 c1 = *(const float4*)(bp + 4);
  o0.x = fmaxf(fmaf(b0a, inv, c0.x), 0.f);
  o0.y = fmaxf(fmaf(b1a, inv, c0.y), 0.f);
  o0.z = fmaxf(fmaf(b2a, inv, c0.z), 0.f);
  o0.w = fmaxf(fmaf(b3a, inv, c0.w), 0.f);
  o1.x = fmaxf(fmaf(b4a, inv, c1.x), 0.f);
  o1.y = fmaxf(fmaf(b5a, inv, c1.y), 0.f);
  o1.z = fmaxf(fmaf(b6a, inv, c1.z), 0.f);
  o1.w = fmaxf(fmaf(b7a, inv, c1.w), 0.f);
}

// ---------------- fused: gather layer1 + gemm layer2 -------------------------
// Block = 16 nodes (4 waves x 4 nodes each), one barrier, improved core.
__global__ __launch_bounds__(256) void fused_g1_gemm2_k(
    const __half* __restrict__ xlh, const __half* __restrict__ xrh,
    const int* __restrict__ row_start, const int* __restrict__ csr_soff,
    const float* __restrict__ att, const float* __restrict__ bias,
    const _Float16* __restrict__ wb2,
    const float* __restrict__ bl2, const float* __restrict__ br2,
    __half* __restrict__ xlh2, __half* __restrict__ xrh2)
{
  __shared__ ushort xs[16*128];      // 4 KB: swizzled fp16 input rows
  __shared__ ushort outs[16*OSTR];   // 8.3 KB: fp16 output rows, padded stride
  int tid = threadIdx.x;
  int wv = tid >> 6, lane = tid & 63;
  int q4 = lane >> 4, hl = lane & 15;
  int nl = wv*4 + q4;
  int base = blockIdx.x * 16;        // 3125 * 16 = 50000 exact

  // ---- gather phase (layer 1) ----
  float4 o0, o1;
  gather_core(base + nl, lane, xlh, xrh, row_start, csr_soff, att, bias, o0, o1);
  __half2 p0 = __floats2half2_rn(o0.x, o0.y);
  __half2 p1 = __floats2half2_rn(o0.z, o0.w);
  __half2 p2 = __floats2half2_rn(o1.x, o1.y);
  __half2 p3 = __floats2half2_rn(o1.z, o1.w);
  uint4 pk = make_uint4(*(uint*)&p0, *(uint*)&p1, *(uint*)&p2, *(uint*)&p3);
  // row nl, 16B chunk hl, XOR-swizzled so gemm's ds_read_b128 is conflict-free
  *(uint4*)((char*)xs + nl*256 + ((hl*16) ^ ((nl&7)<<4))) = pk;
  __syncthreads();

  // ---- gemm phase (layer 2) ----
  int m = lane & 15, q = lane >> 4;
  f32x4 acc[4];
  #pragma unroll
  for (int g = 0; g < 4; g++) acc[g] = (f32x4)(0.f);
  #pragma unroll
  for (int C = 0; C < 4; C++) {
    hfrag8 ah = *(const hfrag8*)((const char*)xs + m*256 + ((C*64 + q*16) ^ ((m&7)<<4)));
    #pragma unroll
    for (int g = 0; g < 4; g++) {
      int gg = wv*4 + g;
      size_t boff = ((size_t)(C*16 + gg)*64 + lane)*8;
      hfrag8 bh = *(const hfrag8*)(wb2 + boff);
      acc[g] = __builtin_amdgcn_mfma_f32_16x16x32_f16(ah, bh, acc[g], 0, 0, 0);
    }
  }
  // epilogue: bias in f32, RNE cvt, fp16 LDS transpose (padded stride)
  #pragma unroll
  for (int g = 0; g < 4; g++) {
    int gg = wv*4 + g;
    int dim = gg*16 + m;
    float bv = (gg < 8) ? bl2[dim] : br2[dim - 128];
    #pragma unroll
    for (int r = 0; r < 4; r++) {
      int row = q*4 + r;
      __half hv = __float2half_rn(acc[g][r] + bv);
      outs[row*OSTR + gg*16 + m] = *(ushort*)&hv;
    }
  }
  __syncthreads();
  // cooperative coalesced writeout: 16 rows x 256 fp16
  #pragma unroll
  for (int p = 0; p < 2; p++) {
    int c = p*256 + tid;
    int row = c >> 5, off = c & 31;
    uint4 v = *(const uint4*)((const char*)outs + row*(OSTR*2) + off*16);
    int nodeo = base + row;
    int d0 = off*8;
    ushort* dstp = (d0 < 128) ? ((ushort*)xlh2 + (size_t)nodeo*DIM + d0)
                              : ((ushort*)xrh2 + (size_t)nodeo*DIM + (d0 - 128));
    *(uint4*)dstp = v;
  }
}

// ---------------- final gather (layer 2) -> fp32 output ----------------------
__global__ __launch_bounds__(256) void gat_gather2(
    const __half* __restrict__ xlh, const __half* __restrict__ xrh,
    const int* __restrict__ row_start, const int* __restrict__ csr_soff,
    const float* __restrict__ att, const float* __restrict__ bias,
    float* __restrict__ outf)
{
  int wave = (blockIdx.x * 256 + threadIdx.x) >> 6;
  int lane = threadIdx.x & 63;
  int q4 = lane >> 4;
  int hl = lane & 15;
  int node = wave * 4 + q4;                  // 12500 waves * 4 = 50000 exact
  float4 o0, o1;
  gather_core(node, lane, xlh, xrh, row_start, csr_soff, att, bias, o0, o1);
  float* op = outf + (size_t)node*DIM + hl*8;
  *(float4*)(op)     = o0;
  *(float4*)(op + 4) = o1;
}

extern "C" void kernel_launch(void* const* d_in, const int* in_sizes, int n_in,
                              void* d_out, int out_size, void* d_ws, size_t ws_size,
                              hipStream_t stream)
{
  const float* node_fts = (const float*)d_in[0];
  const int*  edge_index = (const int*)d_in[1];
  const float* Wl1 = (const float*)d_in[2];
  const float* bl1 = (const float*)d_in[3];
  const float* Wr1 = (const float*)d_in[4];
  const float* br1 = (const float*)d_in[5];
  const float* att1 = (const float*)d_in[6];
  const float* bias1 = (const float*)d_in[7];
  const float* Wl2 = (const float*)d_in[8];
  const float* bl2 = (const float*)d_in[9];
  const float* Wr2 = (const float*)d_in[10];
  const float* br2 = (const float*)d_in[11];
  const float* att2 = (const float*)d_in[12];
  const float* bias2 = (const float*)d_in[13];
  const int* src = edge_index;
  const int* dst = edge_index + N_EDGES;

  char* ws = (char*)d_ws;
  __half* xlh = (__half*)ws;               ws += (size_t)N_NODES*DIM*2;
  __half* xrh = (__half*)ws;               ws += (size_t)N_NODES*DIM*2;
  __half* xlh2 = (__half*)ws;              ws += (size_t)N_NODES*DIM*2;
  __half* xrh2 = (__half*)ws;              ws += (size_t)N_NODES*DIM*2;
  _Float16* wb = (_Float16*)ws;            ws += 2*4*16*64*8*2;
  int* row_start   = (int*)ws;             ws += (N_NODES+1)*4;
  int* csr_soff    = (int*)ws;             ws += (size_t)N_EDGES*4;
  int* bucket_cnt  = (int*)ws;             ws += KBUCKET*4;
  uint* bucketdata = (uint*)ws;            ws += (size_t)KBUCKET*BCAP*4;

  const int W_LAYER = 4*16*64*8;           // fp16 elems per layer of wb

  int gemm_blocks = (NGROUPS + 3) / 4;     // 782
  int gather_blocks = N_NODES / 16;        // 3125

  // L1: W frags + zero bucket_cnt
  prep_w<<<128, 64, 0, stream>>>(Wl1, Wr1, Wl2, Wr2, wb, bucket_cnt);
  // L2: CSR phase A
  bucket_scatter_k<<<N_EDGES/EPB, 256, 0, stream>>>(src, dst, bucket_cnt, bucketdata);
  // L3: gemm layer1 (wb LDS-staged) + CSR phase B (merged)
  gemm1_csr_k<<<KBUCKET + gemm_blocks, 256, 0, stream>>>(
      node_fts, wb, bl1, br1, xlh, xrh,
      bucket_cnt, bucketdata, row_start, csr_soff);
  // L4: gather layer1 + gemm layer2 fused (4-wave blocks, barrier)
  fused_g1_gemm2_k<<<gather_blocks, 256, 0, stream>>>(
      xlh, xrh, row_start, csr_soff, att1, bias1,
      wb + W_LAYER, bl2, br2, xlh2, xrh2);
  // L5: final gather layer2 -> fp32 out (index-decoupled pipeline)
  gat_gather2<<<gather_blocks, 256, 0, stream>>>(
      xlh2, xrh2, row_start, csr_soff, att2, bias2, (float*)d_out);
}

// Round 9
// 214.530 us; speedup vs baseline: 1.0718x; 1.0010x over previous
//
#include <hip/hip_runtime.h>
#include <hip/hip_bf16.h>
#include <hip/hip_fp16.h>

#define N_NODES 50000
#define N_EDGES 800000
#define DIM 128
#define NGROUPS (N_NODES / 16)                 // 3125 (exact)
#define KBUCKET 196                            // buckets of 256 nodes (dst>>8)
#define BCAP 5120                              // bucket capacity (mean 4096, ~16 sigma)
#define EPB 2000                               // edges per phase-A block (400 blocks)
#define OSTR 260                               // fused outs row stride (ushorts)
#define TSTR 132                               // gemm1 fp16 transpose row stride (ushorts)

typedef __attribute__((ext_vector_type(8))) _Float16 hfrag8;
typedef __attribute__((ext_vector_type(4))) float f32x4;
typedef _Float16 h2 __attribute__((ext_vector_type(2)));

__device__ __forceinline__ h2 u2h(uint u){ union{uint u; h2 h;} c; c.u = u; return c.h; }

// sum across the 16 lanes of a DPP row; all 16 lanes receive the total.
__device__ __forceinline__ float rowsum16(float p) {
  union { float f; int i; } a, b;
  a.f = p;
  b.i = __builtin_amdgcn_update_dpp(0, a.i, 0x128, 0xF, 0xF, true); a.f += b.f;
  b.i = __builtin_amdgcn_update_dpp(0, a.i, 0x124, 0xF, 0xF, true); a.f += b.f;
  b.i = __builtin_amdgcn_update_dpp(0, a.i, 0x122, 0xF, 0xF, true); a.f += b.f;
  b.i = __builtin_amdgcn_update_dpp(0, a.i, 0x121, 0xF, 0xF, true); a.f += b.f;
  return a.f;
}

// ---------------- CSR build phase A: bucket scatter (counting-sort v2) -------
// LDS entry: (bucket << 24) | (src << 8) | (dst & 255); bucket stripped at
// flush so bucketdata format is unchanged. Flush writes are coalesced runs
// (consecutive LDS slots of one bucket -> consecutive global addresses).

__global__ __launch_bounds__(256) void bucket_scatter_k(
    const int* __restrict__ src, const int* __restrict__ dst,
    int* __restrict__ bucket_cnt, uint* __restrict__ bucketdata)
{
  __shared__ int cnt[KBUCKET], cur[KBUCKET];
  __shared__ int lofs[KBUCKET], gbase[KBUCKET];
  __shared__ int wsum[4];
  __shared__ uint spay[EPB];                   // 8 KB: bucket-sorted payloads
  int tid = threadIdx.x;
  int lane = tid & 63, w = tid >> 6;
  for (int t = tid; t < KBUCKET; t += 256) { cnt[t] = 0; cur[t] = 0; }
  __syncthreads();

  int e0 = blockIdx.x * EPB;
  int dreg[8];                                 // cache dst: read once, use twice
  #pragma unroll
  for (int it = 0; it < 8; it++) {
    int i = it*256 + tid;
    dreg[it] = (i < EPB) ? dst[e0 + i] : -1;
    if (i < EPB) atomicAdd(&cnt[dreg[it] >> 8], 1);
  }
  __syncthreads();

  // block-exclusive scan of cnt (256-wide, valid KBUCKET) + global base alloc
  int v = (tid < KBUCKET) ? cnt[tid] : 0;
  int inc = v;
  #pragma unroll
  for (int off = 1; off < 64; off <<= 1) {
    int y = __shfl_up(inc, off, 64);
    if (lane >= off) inc += y;
  }
  if (lane == 63) wsum[w] = inc;
  __syncthreads();
  int wpre = 0;
  #pragma unroll
  for (int i = 0; i < 4; i++) if (i < w) wpre += wsum[i];
  if (tid < KBUCKET) {
    lofs[tid]  = wpre + inc - v;               // exclusive prefix
    gbase[tid] = atomicAdd(&bucket_cnt[tid], v);
  }
  __syncthreads();

  // sort edges into LDS by bucket
  #pragma unroll
  for (int it = 0; it < 8; it++) {
    int i = it*256 + tid;
    if (i < EPB) {
      int s = src[e0 + i], d = dreg[it];
      int b = d >> 8;
      int r = atomicAdd(&cur[b], 1);
      spay[lofs[b] + r] = ((uint)b << 24) | ((uint)s << 8) | (uint)(d & 255);
    }
  }
  __syncthreads();

  // flush: consecutive slots of a bucket -> consecutive global addresses
  #pragma unroll
  for (int it = 0; it < 8; it++) {
    int i = it*256 + tid;
    if (i < EPB) {
      uint e = spay[i];
      int b = (int)(e >> 24);
      int pos = gbase[b] + (i - lofs[b]);
      bucketdata[(size_t)b * BCAP + pos] = e & 0x00FFFFFFu;
    }
  }
}

// ---------------- W fragment prep (fp16) + bucket_cnt zeroing ----------------
__global__ __launch_bounds__(64) void prep_w(
    const float* __restrict__ Wl1, const float* __restrict__ Wr1,
    const float* __restrict__ Wl2, const float* __restrict__ Wr2,
    _Float16* __restrict__ wb, int* __restrict__ bucket_cnt)
{
  int bid = blockIdx.x;            // 2 layers * 4 C * 16 g = 128 blocks
  if (bid == 0) {
    for (int t = threadIdx.x; t < KBUCKET; t += 64) bucket_cnt[t] = 0;
  }
  int layer = bid >> 6, rest = bid & 63;
  int C = rest >> 4, g = rest & 15;
  int lane = threadIdx.x;
  int m = lane & 15, q = lane >> 4;
  int dim = g*16 + m;
  const float* W = layer ? (dim < 128 ? Wl2 : Wr2) : (dim < 128 ? Wl1 : Wr1);
  int dcol = dim & 127;
  _Float16 h[8];
  #pragma unroll
  for (int j = 0; j < 8; j++) {
    int k = C*32 + q*8 + j;
    h[j] = (_Float16)W[(size_t)k*DIM + dcol];
  }
  size_t off = ((size_t)bid*64 + lane)*8;
  *(hfrag8*)(wb + off) = *(hfrag8*)h;
}

// ---------------- merged: gemm layer1 (fp32 in) + CSR phase B ----------------
// gemm path v3: wb C-chunks staged through LDS; wstage ALIASES touts (wstage
// dead after the C loop, touts used only in the epilogue) -> LDS 35->19 KB,
// 4->8 blocks/CU. Extra __syncthreads() after the C loop makes reuse safe.
__global__ __launch_bounds__(256) void gemm1_csr_k(
    const float* __restrict__ x, const _Float16* __restrict__ wb,
    const float* __restrict__ bl, const float* __restrict__ br,
    __half* __restrict__ xlh, __half* __restrict__ xrh,
    const int* __restrict__ bucket_cnt, const uint* __restrict__ bucketdata,
    int* __restrict__ row_start, int* __restrict__ csr_soff)
{
  __shared__ int hist[256], cur[256];        // csr path
  __shared__ int wsumA[4], wsumB[4];
  __shared__ __align__(16) ushort touts[4][16*TSTR];  // 16.9 KB; low 16 KB = wstage
  int tid = threadIdx.x;

  if (blockIdx.x < KBUCKET) {
    // ---- bucket_csr path (unchanged) ----
    int b = blockIdx.x;
    int lane = tid & 63, w = tid >> 6;
    int vv = (tid < b) ? bucket_cnt[tid] : 0;
    #pragma unroll
    for (int off = 32; off > 0; off >>= 1) vv += __shfl_xor(vv, off, 64);
    if (lane == 0) wsumA[w] = vv;
    hist[tid] = 0;
    __syncthreads();
    int base_csr = wsumA[0] + wsumA[1] + wsumA[2] + wsumA[3];
    int cnt = bucket_cnt[b];
    int node0 = b << 8;
    const uint* bd = bucketdata + (size_t)b * BCAP;
    for (int i = tid; i < cnt; i += 256)
      atomicAdd(&hist[bd[i] & 255], 1);
    __syncthreads();
    int v = hist[tid];
    int inc = v;
    #pragma unroll
    for (int off = 1; off < 64; off <<= 1) {
      int y = __shfl_up(inc, off, 64);
      if (lane >= off) inc += y;
    }
    if (lane == 63) wsumB[w] = inc;
    __syncthreads();
    int wpre = 0;
    #pragma unroll
    for (int i = 0; i < 4; i++) if (i < w) wpre += wsumB[i];
    int excl = wpre + inc - v;
    int node = node0 + tid;
    if (node < N_NODES) row_start[node] = base_csr + excl;
    if (b == 0 && tid == 0) row_start[N_NODES] = N_EDGES;
    cur[tid] = excl;
    __syncthreads();
    for (int i = tid; i < cnt; i += 256) {
      uint p = bd[i];
      int r = atomicAdd(&cur[p & 255], 1);
      csr_soff[base_csr + r] = (int)(p & 0xFFFFFF00u);  // src*256 byte offset
    }
    return;
  }

  // ---- gemm path (layer 1, fp32 input), wb LDS-staged ----
  int wv = tid >> 6, lane = tid & 63;
  int G = (blockIdx.x - KBUCKET) * 4 + wv;
  bool wvalid = (G < NGROUPS);
  if (!wvalid) G = NGROUPS - 1;              // clamp: loads safe, writes guarded

  _Float16* wstage = (_Float16*)&touts[0][0];   // alias (16 KB region)
  int m = lane & 15, q = lane >> 4;
  const float* xrow = x + (size_t)(G*16 + m)*DIM + q*8;

  f32x4 acc[16];
  #pragma unroll
  for (int g = 0; g < 16; g++) acc[g] = (f32x4)(0.f);

  #pragma unroll 1
  for (int C = 0; C < 4; C++) {
    __syncthreads();                         // wstage reuse from previous C
    {                                        // cooperative 16-KB chunk stage
      const uint4* srcw = (const uint4*)(wb + (size_t)C*16*64*8);
      uint4* dstw = (uint4*)wstage;
      #pragma unroll
      for (int k = 0; k < 4; k++)
        dstw[k*256 + tid] = srcw[k*256 + tid];
    }
    __syncthreads();
    float v[8];
    *(float4*)(v)     = *(const float4*)(xrow + C*32);
    *(float4*)(v + 4) = *(const float4*)(xrow + C*32 + 4);
    _Float16 hh[8];
    #pragma unroll
    for (int j = 0; j < 8; j++) hh[j] = (_Float16)v[j];
    hfrag8 ah = *(hfrag8*)hh;
    #pragma unroll
    for (int g = 0; g < 16; g++) {
      hfrag8 bh = *(const hfrag8*)(wstage + ((size_t)g*64 + lane)*8);
      acc[g] = __builtin_amdgcn_mfma_f32_16x16x32_f16(ah, bh, acc[g], 0, 0, 0);
    }
  }
  __syncthreads();                           // all waves done with wstage

  // epilogue: bias f32, RNE cvt, fp16 per-wave transpose (wave-internal order)
  ushort* tw = touts[wv];
  #pragma unroll
  for (int half = 0; half < 2; half++) {
    const float* B = half ? br : bl;
    ushort* outh = half ? (ushort*)xrh : (ushort*)xlh;
    #pragma unroll
    for (int g = 0; g < 8; g++) {
      float bv = B[g*16 + m];
      #pragma unroll
      for (int r = 0; r < 4; r++) {
        __half hv = __float2half_rn(acc[half*8 + g][r] + bv);
        tw[(q*4 + r)*TSTR + g*16 + m] = *(ushort*)&hv;
      }
    }
    // coalesced per-wave writeout: 16 rows x 128 fp16 = 256 x 16B chunks
    #pragma unroll
    for (int i = 0; i < 4; i++) {
      int c = i*64 + lane;
      int row = c >> 4, off = c & 15;
      uint4 vv = *(const uint4*)((const char*)tw + row*(TSTR*2) + off*16);
      if (wvalid)
        *(uint4*)(outh + (size_t)(G*16 + row)*DIM + off*8) = vv;
    }
  }
}

// ---------------- gather core: one node per 16-lane group --------------------
// Indices of the first <=32 edges preloaded lane-parallel (my1 only when
// needed), distributed per-batch via ds_bpermute; row loads pipeline A/B.
// exp2f via att prescaled by log2e; DPP row reduction; masked tail batch.

#define GAT_IDX(OFF, TBASE)                                             \
  do {                                                                  \
    if ((TBASE) < 32) {                                                 \
      int _src = ((TBASE) < 16) ? my0 : my1;                            \
      _Pragma("unroll")                                                 \
      for (int j = 0; j < 4; j++)                                       \
        OFF[j] = __builtin_amdgcn_ds_bpermute(                          \
                     grpb4 + ((((TBASE) + j) & 15) << 2), _src);        \
    } else {                                                            \
      _Pragma("unroll")                                                 \
      for (int j = 0; j < 4; j++)                                       \
        OFF[j] = csr_soff[min(r0 + (TBASE) + j, last)];                 \
    }                                                                   \
  } while (0)

#define GAT_LDR4(OFF, RAW)                                              \
  _Pragma("unroll")                                                     \
  for (int j = 0; j < 4; j++)                                           \
    RAW[j] = *(const uint4*)(xb + (size_t)(uint)OFF[j]);

#define GAT_BODY(RAW, WEXPR)                                            \
  _Pragma("unroll")                                                     \
  for (int j = 0; j < 4; j++) {                                         \
    h2 v01 = u2h(RAW[j].x), v23 = u2h(RAW[j].y);                        \
    h2 v45 = u2h(RAW[j].z), v67 = u2h(RAW[j].w);                        \
    h2 s01 = v01 + xr01, s23 = v23 + xr23;                              \
    h2 s45 = v45 + xr45, s67 = v67 + xr67;                              \
    s01 = __builtin_elementwise_max(s01, s01 * c02);                    \
    s23 = __builtin_elementwise_max(s23, s23 * c02);                    \
    s45 = __builtin_elementwise_max(s45, s45 * c02);                    \
    s67 = __builtin_elementwise_max(s67, s67 * c02);                    \
    float pA = __builtin_amdgcn_fdot2(s01, a01, 0.f, false);            \
    pA = __builtin_amdgcn_fdot2(s23, a23, pA, false);                   \
    float pB = __builtin_amdgcn_fdot2(s45, a45, 0.f, false);            \
    pB = __builtin_amdgcn_fdot2(s67, a67, pB, false);                   \
    float p = rowsum16(pA + pB);                                        \
    float w = (WEXPR);                                                  \
    l += w;                                                             \
    b0a = fmaf(w, (float)v01.x, b0a); b1a = fmaf(w, (float)v01.y, b1a); \
    b2a = fmaf(w, (float)v23.x, b2a); b3a = fmaf(w, (float)v23.y, b3a); \
    b4a = fmaf(w, (float)v45.x, b4a); b5a = fmaf(w, (float)v45.y, b5a); \
    b6a = fmaf(w, (float)v67.x, b6a); b7a = fmaf(w, (float)v67.y, b7a); \
  }

__device__ __forceinline__ void gather_core(
    int node, int lane,
    const __half* __restrict__ xlh, const __half* __restrict__ xrh,
    const int* __restrict__ row_start, const int* __restrict__ csr_soff,
    const float* __restrict__ att, const float* __restrict__ bias,
    float4& o0, float4& o1)
{
  int hl = lane & 15;
  int grpb4 = (lane & 48) << 2;              // byte addr of group's lane 0
  int r0 = row_start[node];
  int deg = row_start[node + 1] - r0;
  int last = r0 + deg - 1;

  // preload first <=32 edge indices (clamped; my1 only when batches need it)
  int my0 = 0, my1 = 0;
  if (deg > 0)  my0 = csr_soff[min(r0 + hl,      last)];
  if (deg > 16) my1 = csr_soff[min(r0 + 16 + hl, last)];

  uint4 rx = *(const uint4*)((const ushort*)xrh + (size_t)node*DIM + hl*8);
  h2 xr01 = u2h(rx.x), xr23 = u2h(rx.y), xr45 = u2h(rx.z), xr67 = u2h(rx.w);
  const float* ap = att + hl*8;
  float4 af0 = *(const float4*)(ap);
  float4 af1 = *(const float4*)(ap + 4);
  const float L2E = 1.44269504088896f;       // exp(p) == exp2(p*log2e)
  h2 a01 = {(_Float16)(af0.x*L2E), (_Float16)(af0.y*L2E)};
  h2 a23 = {(_Float16)(af0.z*L2E), (_Float16)(af0.w*L2E)};
  h2 a45 = {(_Float16)(af1.x*L2E), (_Float16)(af1.y*L2E)};
  h2 a67 = {(_Float16)(af1.z*L2E), (_Float16)(af1.w*L2E)};
  const h2 c02 = {(_Float16)0.2f, (_Float16)0.2f};

  float l = 0.f;
  float b0a=0,b1a=0,b2a=0,b3a=0,b4a=0,b5a=0,b6a=0,b7a=0;
  const char* xb = (const char*)xlh + hl*16;

  int offA[4]; uint4 rawA[4];
  int offB[4]; uint4 rawB[4];
  int nfull = deg & ~3;

  if (nfull > 0) { GAT_IDX(offA, 0); GAT_LDR4(offA, rawA); }
  #pragma unroll 1
  for (int t = 0; t < nfull; t += 8) {
    bool hasB = (t + 4 < nfull);
    if (hasB) { GAT_IDX(offB, t + 4); GAT_LDR4(offB, rawB); }
    GAT_BODY(rawA, exp2f(p));
    if (t + 8 < nfull) { GAT_IDX(offA, t + 8); GAT_LDR4(offA, rawA); }
    if (hasB) GAT_BODY(rawB, exp2f(p));
  }
  int rem = deg - nfull;
  if (rem > 0) {                             // masked tail batch (1..3 edges)
    #pragma unroll
    for (int j = 0; j < 4; j++)
      offA[j] = csr_soff[min(r0 + nfull + j, last)];
    GAT_LDR4(offA, rawA);
    GAT_BODY(rawA, (j < rem) ? exp2f(p) : 0.f);
  }

  float inv = 1.f / fmaxf(l, 1e-16f);
  const float* bp = bias + hl*8;
  float4 c0 = *(const float4*)(bp);
  float4 c1 = *(const float4*)(bp + 4);
  o0.x = fmaxf(fmaf(b0a, inv, c0.x), 0.f);
  o0.y = fmaxf(fmaf(b1a, inv, c0.y), 0.f);
  o0.z = fmaxf(fmaf(b2a, inv, c0.z), 0.f);
  o0.w = fmaxf(fmaf(b3a, inv, c0.w), 0.f);
  o1.x = fmaxf(fmaf(b4a, inv, c1.x), 0.f);
  o1.y = fmaxf(fmaf(b5a, inv, c1.y), 0.f);
  o1.z = fmaxf(fmaf(b6a, inv, c1.z), 0.f);
  o1.w = fmaxf(fmaf(b7a, inv, c1.w), 0.f);
}

// ---------------- fused: gather layer1 + gemm layer2 -------------------------
// Block = 16 nodes (4 waves x 4 nodes each), one barrier, improved core.
__global__ __launch_bounds__(256) void fused_g1_gemm2_k(
    const __half* __restrict__ xlh, const __half* __restrict__ xrh,
    const int* __restrict__ row_start, const int* __restrict__ csr_soff,
    const float* __restrict__ att, const float* __restrict__ bias,
    const _Float16* __restrict__ wb2,
    const float* __restrict__ bl2, const float* __restrict__ br2,
    __half* __restrict__ xlh2, __half* __restrict__ xrh2)
{
  __shared__ ushort xs[16*128];      // 4 KB: swizzled fp16 input rows
  __shared__ ushort outs[16*OSTR];   // 8.3 KB: fp16 output rows, padded stride
  int tid = threadIdx.x;
  int wv = tid >> 6, lane = tid & 63;
  int q4 = lane >> 4, hl = lane & 15;
  int nl = wv*4 + q4;
  int base = blockIdx.x * 16;        // 3125 * 16 = 50000 exact

  // ---- gather phase (layer 1) ----
  float4 o0, o1;
  gather_core(base + nl, lane, xlh, xrh, row_start, csr_soff, att, bias, o0, o1);
  __half2 p0 = __floats2half2_rn(o0.x, o0.y);
  __half2 p1 = __floats2half2_rn(o0.z, o0.w);
  __half2 p2 = __floats2half2_rn(o1.x, o1.y);
  __half2 p3 = __floats2half2_rn(o1.z, o1.w);
  uint4 pk = make_uint4(*(uint*)&p0, *(uint*)&p1, *(uint*)&p2, *(uint*)&p3);
  // row nl, 16B chunk hl, XOR-swizzled so gemm's ds_read_b128 is conflict-free
  *(uint4*)((char*)xs + nl*256 + ((hl*16) ^ ((nl&7)<<4))) = pk;
  __syncthreads();

  // ---- gemm phase (layer 2) ----
  int m = lane & 15, q = lane >> 4;
  f32x4 acc[4];
  #pragma unroll
  for (int g = 0; g < 4; g++) acc[g] = (f32x4)(0.f);
  #pragma unroll
  for (int C = 0; C < 4; C++) {
    hfrag8 ah = *(const hfrag8*)((const char*)xs + m*256 + ((C*64 + q*16) ^ ((m&7)<<4)));
    #pragma unroll
    for (int g = 0; g < 4; g++) {
      int gg = wv*4 + g;
      size_t boff = ((size_t)(C*16 + gg)*64 + lane)*8;
      hfrag8 bh = *(const hfrag8*)(wb2 + boff);
      acc[g] = __builtin_amdgcn_mfma_f32_16x16x32_f16(ah, bh, acc[g], 0, 0, 0);
    }
  }
  // epilogue: bias in f32, RNE cvt, fp16 LDS transpose (padded stride)
  #pragma unroll
  for (int g = 0; g < 4; g++) {
    int gg = wv*4 + g;
    int dim = gg*16 + m;
    float bv = (gg < 8) ? bl2[dim] : br2[dim - 128];
    #pragma unroll
    for (int r = 0; r < 4; r++) {
      int row = q*4 + r;
      __half hv = __float2half_rn(acc[g][r] + bv);
      outs[row*OSTR + gg*16 + m] = *(ushort*)&hv;
    }
  }
  __syncthreads();
  // cooperative coalesced writeout: 16 rows x 256 fp16
  #pragma unroll
  for (int p = 0; p < 2; p++) {
    int c = p*256 + tid;
    int row = c >> 5, off = c & 31;
    uint4 v = *(const uint4*)((const char*)outs + row*(OSTR*2) + off*16);
    int nodeo = base + row;
    int d0 = off*8;
    ushort* dstp = (d0 < 128) ? ((ushort*)xlh2 + (size_t)nodeo*DIM + d0)
                              : ((ushort*)xrh2 + (size_t)nodeo*DIM + (d0 - 128));
    *(uint4*)dstp = v;
  }
}

// ---------------- final gather (layer 2) -> fp32 output ----------------------
__global__ __launch_bounds__(256) void gat_gather2(
    const __half* __restrict__ xlh, const __half* __restrict__ xrh,
    const int* __restrict__ row_start, const int* __restrict__ csr_soff,
    const float* __restrict__ att, const float* __restrict__ bias,
    float* __restrict__ outf)
{
  int wave = (blockIdx.x * 256 + threadIdx.x) >> 6;
  int lane = threadIdx.x & 63;
  int q4 = lane >> 4;
  int hl = lane & 15;
  int node = wave * 4 + q4;                  // 12500 waves * 4 = 50000 exact
  float4 o0, o1;
  gather_core(node, lane, xlh, xrh, row_start, csr_soff, att, bias, o0, o1);
  float* op = outf + (size_t)node*DIM + hl*8;
  *(float4*)(op)     = o0;
  *(float4*)(op + 4) = o1;
}

extern "C" void kernel_launch(void* const* d_in, const int* in_sizes, int n_in,
                              void* d_out, int out_size, void* d_ws, size_t ws_size,
                              hipStream_t stream)
{
  const float* node_fts = (const float*)d_in[0];
  const int*  edge_index = (const int*)d_in[1];
  const float* Wl1 = (const float*)d_in[2];
  const float* bl1 = (const float*)d_in[3];
  const float* Wr1 = (const float*)d_in[4];
  const float* br1 = (const float*)d_in[5];
  const float* att1 = (const float*)d_in[6];
  const float* bias1 = (const float*)d_in[7];
  const float* Wl2 = (const float*)d_in[8];
  const float* bl2 = (const float*)d_in[9];
  const float* Wr2 = (const float*)d_in[10];
  const float* br2 = (const float*)d_in[11];
  const float* att2 = (const float*)d_in[12];
  const float* bias2 = (const float*)d_in[13];
  const int* src = edge_index;
  const int* dst = edge_index + N_EDGES;

  char* ws = (char*)d_ws;
  __half* xlh = (__half*)ws;               ws += (size_t)N_NODES*DIM*2;
  __half* xrh = (__half*)ws;               ws += (size_t)N_NODES*DIM*2;
  __half* xlh2 = (__half*)ws;              ws += (size_t)N_NODES*DIM*2;
  __half* xrh2 = (__half*)ws;              ws += (size_t)N_NODES*DIM*2;
  _Float16* wb = (_Float16*)ws;            ws += 2*4*16*64*8*2;
  int* row_start   = (int*)ws;             ws += (N_NODES+1)*4;
  int* csr_soff    = (int*)ws;             ws += (size_t)N_EDGES*4;
  int* bucket_cnt  = (int*)ws;             ws += KBUCKET*4;
  uint* bucketdata = (uint*)ws;            ws += (size_t)KBUCKET*BCAP*4;

  const int W_LAYER = 4*16*64*8;           // fp16 elems per layer of wb

  int gemm_blocks = (NGROUPS + 3) / 4;     // 782
  int gather_blocks = N_NODES / 16;        // 3125

  // L1: W frags + zero bucket_cnt
  prep_w<<<128, 64, 0, stream>>>(Wl1, Wr1, Wl2, Wr2, wb, bucket_cnt);
  // L2: CSR phase A (counting-sort, coalesced bucketdata writes)
  bucket_scatter_k<<<N_EDGES/EPB, 256, 0, stream>>>(src, dst, bucket_cnt, bucketdata);
  // L3: gemm layer1 (wb LDS-staged, aliased LDS) + CSR phase B (merged)
  gemm1_csr_k<<<KBUCKET + gemm_blocks, 256, 0, stream>>>(
      node_fts, wb, bl1, br1, xlh, xrh,
      bucket_cnt, bucketdata, row_start, csr_soff);
  // L4: gather layer1 + gemm layer2 fused (4-wave blocks, barrier)
  fused_g1_gemm2_k<<<gather_blocks, 256, 0, stream>>>(
      xlh, xrh, row_start, csr_soff, att1, bias1,
      wb + W_LAYER, bl2, br2, xlh2, xrh2);
  // L5: final gather layer2 -> fp32 out (index-decoupled pipeline)
  gat_gather2<<<gather_blocks, 256, 0, stream>>>(
      xlh2, xrh2, row_start, csr_soff, att2, bias2, (float*)d_out);
}